// Round 6
// baseline (727.483 us; speedup 1.0000x reference)
//
#include <hip/hip_runtime.h>
#include <hip/hip_fp16.h>

#define E_EDGES 320000
#define NF 20

__device__ __forceinline__ float selu_f(float x) {
    const float scale = 1.0507009873554805f;
    const float alpha = 1.6732632423543772f;
    return x > 0.f ? scale * x : scale * alpha * (__expf(x) - 1.f);
}
__device__ __forceinline__ float sigmoid_f(float x) {
    return 1.f / (1.f + __expf(-x));
}
__device__ __forceinline__ float4 f4z() { return make_float4(0.f, 0.f, 0.f, 0.f); }
__device__ __forceinline__ float4 f4fma(float a, float4 b, float4 c) {
    c.x = fmaf(a, b.x, c.x); c.y = fmaf(a, b.y, c.y);
    c.z = fmaf(a, b.z, c.z); c.w = fmaf(a, b.w, c.w); return c;
}
__device__ __forceinline__ float4 f4add(float4 a, float4 b) {
    return make_float4(a.x + b.x, a.y + b.y, a.z + b.z, a.w + b.w);
}
__device__ __forceinline__ float4 selu4(float4 x) {
    x.x = selu_f(x.x); x.y = selu_f(x.y); x.z = selu_f(x.z); x.w = selu_f(x.w); return x;
}
__device__ __forceinline__ float dot20(float4 a0, float4 a1, float4 a2, float4 a3, float4 a4,
                                       const float4* __restrict__ w) {
    float4 w0 = w[0], w1 = w[1], w2 = w[2], w3 = w[3], w4 = w[4];
    float r = a0.x * w0.x;
    r = fmaf(a0.y, w0.y, r); r = fmaf(a0.z, w0.z, r); r = fmaf(a0.w, w0.w, r);
    r = fmaf(a1.x, w1.x, r); r = fmaf(a1.y, w1.y, r); r = fmaf(a1.z, w1.z, r); r = fmaf(a1.w, w1.w, r);
    r = fmaf(a2.x, w2.x, r); r = fmaf(a2.y, w2.y, r); r = fmaf(a2.z, w2.z, r); r = fmaf(a2.w, w2.w, r);
    r = fmaf(a3.x, w3.x, r); r = fmaf(a3.y, w3.y, r); r = fmaf(a3.z, w3.z, r); r = fmaf(a3.w, w3.w, r);
    r = fmaf(a4.x, w4.x, r); r = fmaf(a4.y, w4.y, r); r = fmaf(a4.z, w4.z, r); r = fmaf(a4.w, w4.w, r);
    return r;
}
// one LDS row read serves BOTH edges
__device__ __forceinline__ void dot20_dual(const float4* __restrict__ w,
    float4 a0, float4 a1, float4 a2, float4 a3, float4 a4,
    float4 b0, float4 b1, float4 b2, float4 b3, float4 b4,
    float& r0, float& r1)
{
    float4 w0 = w[0], w1 = w[1], w2 = w[2], w3 = w[3], w4 = w[4];
    float r = a0.x * w0.x;
    r = fmaf(a0.y, w0.y, r); r = fmaf(a0.z, w0.z, r); r = fmaf(a0.w, w0.w, r);
    r = fmaf(a1.x, w1.x, r); r = fmaf(a1.y, w1.y, r); r = fmaf(a1.z, w1.z, r); r = fmaf(a1.w, w1.w, r);
    r = fmaf(a2.x, w2.x, r); r = fmaf(a2.y, w2.y, r); r = fmaf(a2.z, w2.z, r); r = fmaf(a2.w, w2.w, r);
    r = fmaf(a3.x, w3.x, r); r = fmaf(a3.y, w3.y, r); r = fmaf(a3.z, w3.z, r); r = fmaf(a3.w, w3.w, r);
    r = fmaf(a4.x, w4.x, r); r = fmaf(a4.y, w4.y, r); r = fmaf(a4.z, w4.z, r); r = fmaf(a4.w, w4.w, r);
    r0 = r;
    float s = b0.x * w0.x;
    s = fmaf(b0.y, w0.y, s); s = fmaf(b0.z, w0.z, s); s = fmaf(b0.w, w0.w, s);
    s = fmaf(b1.x, w1.x, s); s = fmaf(b1.y, w1.y, s); s = fmaf(b1.z, w1.z, s); s = fmaf(b1.w, w1.w, s);
    s = fmaf(b2.x, w2.x, s); s = fmaf(b2.y, w2.y, s); s = fmaf(b2.z, w2.z, s); s = fmaf(b2.w, w2.w, s);
    s = fmaf(b3.x, w3.x, s); s = fmaf(b3.y, w3.y, s); s = fmaf(b3.z, w3.z, s); s = fmaf(b3.w, w3.w, s);
    s = fmaf(b4.x, w4.x, s); s = fmaf(b4.y, w4.y, s); s = fmaf(b4.z, w4.z, s); s = fmaf(b4.w, w4.w, s);
    r1 = s;
}
__device__ __forceinline__ float dot4(float4 a, float4 b) {
    float r = a.x * b.x; r = fmaf(a.y, b.y, r); r = fmaf(a.z, b.z, r); r = fmaf(a.w, b.w, r);
    return r;
}
// 8 packed halves (uint4) -> two float4
__device__ __forceinline__ void h8_to_f4x2(uint4 r, float4& lo, float4& hi) {
    float2 fa = __half22float2(__builtin_bit_cast(__half2, r.x));
    float2 fb = __half22float2(__builtin_bit_cast(__half2, r.y));
    float2 fc = __half22float2(__builtin_bit_cast(__half2, r.z));
    float2 fd = __half22float2(__builtin_bit_cast(__half2, r.w));
    lo = make_float4(fa.x, fa.y, fb.x, fb.y);
    hi = make_float4(fc.x, fc.y, fd.x, fd.y);
}
__device__ __forceinline__ uint4 f8_to_h8(float4 lo, float4 hi) {
    uint4 r;
    r.x = __builtin_bit_cast(unsigned, __floats2half2_rn(lo.x, lo.y));
    r.y = __builtin_bit_cast(unsigned, __floats2half2_rn(lo.z, lo.w));
    r.z = __builtin_bit_cast(unsigned, __floats2half2_rn(hi.x, hi.y));
    r.w = __builtin_bit_cast(unsigned, __floats2half2_rn(hi.z, hi.w));
    return r;
}

#define FOR20(X) \
  X(0, v0.x) X(1, v0.y) X(2, v0.z) X(3, v0.w) \
  X(4, v1.x) X(5, v1.y) X(6, v1.z) X(7, v1.w) \
  X(8, v2.x) X(9, v2.y) X(10, v2.z) X(11, v2.w) \
  X(12, v3.x) X(13, v3.y) X(14, v3.z) X(15, v3.w) \
  X(16, v4.x) X(17, v4.y) X(18, v4.z) X(19, v4.w)

#define FOR20_2(X) \
  X(0, va0.x, vb0.x) X(1, va0.y, vb0.y) X(2, va0.z, vb0.z) X(3, va0.w, vb0.w) \
  X(4, va1.x, vb1.x) X(5, va1.y, vb1.y) X(6, va1.z, vb1.z) X(7, va1.w, vb1.w) \
  X(8, va2.x, vb2.x) X(9, va2.y, vb2.y) X(10, va2.z, vb2.z) X(11, va2.w, vb2.w) \
  X(12, va3.x, vb3.x) X(13, va3.y, vb3.y) X(14, va3.z, vb3.z) X(15, va3.w, vb3.w) \
  X(16, va4.x, vb4.x) X(17, va4.y, vb4.y) X(18, va4.z, vb4.z) X(19, va4.w, vb4.w)

#define FOR8S2(X) \
  X(0, sa0.x, sb0.x) X(1, sa0.y, sb0.y) X(2, sa0.z, sb0.z) X(3, sa0.w, sb0.w) \
  X(4, sa1.x, sb1.x) X(5, sa1.y, sb1.y) X(6, sa1.z, sb1.z) X(7, sa1.w, sb1.w)

// initial B table (fp16) from edge_attr
__global__ void __launch_bounds__(256) kernel_B0(
    const float* __restrict__ h, const float* __restrict__ W1,
    const float* __restrict__ b1, __half* __restrict__ B)
{
    __shared__ __align__(16) float sw[640];
    __shared__ __align__(16) float sbias[32];
    for (int i = threadIdx.x; i < 640; i += 256) sw[i] = W1[640 + i];
    if (threadIdx.x < 32) sbias[threadIdx.x] = b1[threadIdx.x];
    __syncthreads();
    int e = blockIdx.x * 256 + threadIdx.x;
    const float4* hp = reinterpret_cast<const float4*>(h + (size_t)e * NF);
    float4 v0 = hp[0], v1 = hp[1], v2 = hp[2], v3 = hp[3], v4 = hp[4];
    const float4* bi = reinterpret_cast<const float4*>(sbias);
    float4 c0 = bi[0], c1 = bi[1], c2 = bi[2], c3 = bi[3],
           c4 = bi[4], c5 = bi[5], c6 = bi[6], c7 = bi[7];
    #define BSTEP(f, hf) { float t_ = (hf); const float4* w_ = (const float4*)&sw[(f)*32]; \
        c0 = f4fma(t_, w_[0], c0); c1 = f4fma(t_, w_[1], c1); \
        c2 = f4fma(t_, w_[2], c2); c3 = f4fma(t_, w_[3], c3); \
        c4 = f4fma(t_, w_[4], c4); c5 = f4fma(t_, w_[5], c5); \
        c6 = f4fma(t_, w_[6], c6); c7 = f4fma(t_, w_[7], c7); }
    FOR20(BSTEP)
    #undef BSTEP
    uint4* Bp = reinterpret_cast<uint4*>(B + (size_t)e * 32);
    Bp[0] = f8_to_h8(c0, c1); Bp[1] = f8_to_h8(c2, c3);
    Bp[2] = f8_to_h8(c4, c5); Bp[3] = f8_to_h8(c6, c7);
}

// select this lane's old-h channel (i fixed, q runtime)
#define QSEL(x0, x1, x2, x3) (q < 2 ? (q == 0 ? (x0) : (x1)) : (q == 2 ? (x2) : (x3)))

// One step + fused B-write for the NEXT step. 4 lanes/quad, 2 edges/thread.
// B table is fp16 (halves gather bytes + load count vs fp32).
template<int WRITE_B>
__global__ void __launch_bounds__(256) kernel_step(
    const float* __restrict__ h_in, float* __restrict__ h_out,
    const __half* __restrict__ Br, __half* __restrict__ Bw,
    const int* __restrict__ dst,
    const float* __restrict__ W1, const float* __restrict__ b1,
    const float* __restrict__ W2, const float* __restrict__ b2,
    const float* __restrict__ Wih, const float* __restrict__ Whh,
    const float* __restrict__ bih, const float* __restrict__ bhh)
{
    __shared__ __align__(16) float sW1[640];   // rows 0-19 of msg_W1 (20,32)
    __shared__ __align__(16) float sW1b[640];  // rows 20-39 (for fused B-write)
    __shared__ __align__(16) float sW2[640];   // (32,20)
    __shared__ __align__(16) float sb2v[20];
    __shared__ __align__(16) float sb1v[32];
    __shared__ __align__(16) float sWih[1200]; // (60,20)
    __shared__ __align__(16) float sWhh[1200];
    __shared__ float sbih[60];
    __shared__ float sbhh[60];
    for (int i = threadIdx.x; i < 640; i += 256) {
        sW1[i] = W1[i]; sW1b[i] = W1[640 + i]; sW2[i] = W2[i];
    }
    for (int i = threadIdx.x; i < 1200; i += 256) { sWih[i] = Wih[i]; sWhh[i] = Whh[i]; }
    if (threadIdx.x < 20) sb2v[threadIdx.x] = b2[threadIdx.x];
    else if (threadIdx.x >= 32 && threadIdx.x < 64) sb1v[threadIdx.x - 32] = b1[threadIdx.x - 32];
    else if (threadIdx.x >= 64 && threadIdx.x < 124) sbih[threadIdx.x - 64] = bih[threadIdx.x - 64];
    else if (threadIdx.x >= 128 && threadIdx.x < 188) sbhh[threadIdx.x - 128] = bhh[threadIdx.x - 128];
    __syncthreads();

    int t = blockIdx.x * 256 + threadIdx.x;
    int p = t >> 2;
    int q = t & 3;
    int ob = q * 8;
    int e0 = p * 2, e1 = p * 2 + 1;

    int2 dd = *reinterpret_cast<const int2*>(dst + e0);
    int d0 = dd.x, d1 = dd.y;

    const float4* hp0 = reinterpret_cast<const float4*>(h_in + (size_t)e0 * NF);
    const float4* hp1 = reinterpret_cast<const float4*>(h_in + (size_t)e1 * NF);
    float4 va0 = hp0[0], va1 = hp0[1], va2 = hp0[2], va3 = hp0[3], va4 = hp0[4];
    float4 vb0 = hp1[0], vb1 = hp1[1], vb2 = hp1[2], vb3 = hp1[3], vb4 = hp1[4];

    // A slices for both edges (shared LDS weight reads)
    float4 aa0 = f4z(), aa1 = f4z(), ab0 = f4z(), ab1 = f4z();
    #define ASTEP2(f, h0, h1) { const float4* w_ = (const float4*)&sW1[(f)*32 + ob]; \
        float4 w0_ = w_[0], w1_ = w_[1]; \
        aa0 = f4fma((h0), w0_, aa0); aa1 = f4fma((h0), w1_, aa1); \
        ab0 = f4fma((h1), w0_, ab0); ab1 = f4fma((h1), w1_, ab1); }
    FOR20_2(ASTEP2)
    #undef ASTEP2

    // gather 16 fp16 rows per edge; 1 dwordx4 per row per edge (= lane's 8 chans)
    const uint4* Bp0 = reinterpret_cast<const uint4*>(Br) + (size_t)d0 * 64 + q;
    const uint4* Bp1 = reinterpret_cast<const uint4*>(Br) + (size_t)d1 * 64 + q;
    float4 sa0 = f4z(), sa1 = f4z(), sb0 = f4z(), sb1 = f4z();
    #pragma unroll 4
    for (int k = 0; k < 16; k++) {
        uint4 rA = Bp0[k * 4];
        uint4 rB = Bp1[k * 4];
        float4 loA, hiA, loB, hiB;
        h8_to_f4x2(rA, loA, hiA);
        h8_to_f4x2(rB, loB, hiB);
        sa0 = f4add(sa0, selu4(f4add(aa0, loA)));
        sa1 = f4add(sa1, selu4(f4add(aa1, hiA)));
        sb0 = f4add(sb0, selu4(f4add(ab0, loB)));
        sb1 = f4add(sb1, selu4(f4add(ab1, hiB)));
    }

    // partial agg (shared W2 rows)
    float4 ga0 = f4z(), ga1 = f4z(), ga2 = f4z(), ga3 = f4z(), ga4 = f4z();
    float4 gb0 = f4z(), gb1 = f4z(), gb2 = f4z(), gb3 = f4z(), gb4 = f4z();
    #define AGGS2(j, c0_, c1_) { const float4* w_ = (const float4*)&sW2[(ob + (j)) * 20]; \
        float4 w0_ = w_[0], w1_ = w_[1], w2_ = w_[2], w3_ = w_[3], w4_ = w_[4]; \
        float u_ = (c0_), v_ = (c1_); \
        ga0 = f4fma(u_, w0_, ga0); ga1 = f4fma(u_, w1_, ga1); ga2 = f4fma(u_, w2_, ga2); \
        ga3 = f4fma(u_, w3_, ga3); ga4 = f4fma(u_, w4_, ga4); \
        gb0 = f4fma(v_, w0_, gb0); gb1 = f4fma(v_, w1_, gb1); gb2 = f4fma(v_, w2_, gb2); \
        gb3 = f4fma(v_, w3_, gb3); gb4 = f4fma(v_, w4_, gb4); }
    FOR8S2(AGGS2)
    #undef AGGS2

    // quad butterfly
    #define BF1(r_, m_) r_.x += __shfl_xor(r_.x, m_); r_.y += __shfl_xor(r_.y, m_); \
                        r_.z += __shfl_xor(r_.z, m_); r_.w += __shfl_xor(r_.w, m_);
    #define BFLY(m_) BF1(ga0, m_) BF1(ga1, m_) BF1(ga2, m_) BF1(ga3, m_) BF1(ga4, m_) \
                     BF1(gb0, m_) BF1(gb1, m_) BF1(gb2, m_) BF1(gb3, m_) BF1(gb4, m_)
    BFLY(1)
    BFLY(2)
    #undef BFLY
    #undef BF1

    {
        const float4* b2p = reinterpret_cast<const float4*>(sb2v);
        float4 c0 = b2p[0], c1 = b2p[1], c2 = b2p[2], c3 = b2p[3], c4 = b2p[4];
        ga0 = f4fma(16.f, c0, ga0); ga1 = f4fma(16.f, c1, ga1); ga2 = f4fma(16.f, c2, ga2);
        ga3 = f4fma(16.f, c3, ga3); ga4 = f4fma(16.f, c4, ga4);
        gb0 = f4fma(16.f, c0, gb0); gb1 = f4fma(16.f, c1, gb1); gb2 = f4fma(16.f, c2, gb2);
        gb3 = f4fma(16.f, c3, gb3); gb4 = f4fma(16.f, c4, gb4);
    }

    // GRU: channels q*5+i, named outputs (needed for fused B-write)
    float hA0, hA1, hA2, hA3, hA4, hB0, hB1, hB2, hB3, hB4;
    #define GRUCH(i, outA, outB, oldA, oldB) { \
        const int c = q * 5 + (i); \
        float irA, irB, izA, izB, inA, inB, hrA, hrB, hzA, hzB, hnA, hnB; \
        dot20_dual((const float4*)&sWih[c * 20],        ga0, ga1, ga2, ga3, ga4, gb0, gb1, gb2, gb3, gb4, irA, irB); \
        dot20_dual((const float4*)&sWih[(20 + c) * 20], ga0, ga1, ga2, ga3, ga4, gb0, gb1, gb2, gb3, gb4, izA, izB); \
        dot20_dual((const float4*)&sWih[(40 + c) * 20], ga0, ga1, ga2, ga3, ga4, gb0, gb1, gb2, gb3, gb4, inA, inB); \
        dot20_dual((const float4*)&sWhh[c * 20],        va0, va1, va2, va3, va4, vb0, vb1, vb2, vb3, vb4, hrA, hrB); \
        dot20_dual((const float4*)&sWhh[(20 + c) * 20], va0, va1, va2, va3, va4, vb0, vb1, vb2, vb3, vb4, hzA, hzB); \
        dot20_dual((const float4*)&sWhh[(40 + c) * 20], va0, va1, va2, va3, va4, vb0, vb1, vb2, vb3, vb4, hnA, hnB); \
        float bi_r = sbih[c], bi_z = sbih[20 + c], bi_n = sbih[40 + c]; \
        float bh_r = sbhh[c], bh_z = sbhh[20 + c], bh_n = sbhh[40 + c]; \
        { float r = sigmoid_f(bi_r + irA + bh_r + hrA); \
          float z = sigmoid_f(bi_z + izA + bh_z + hzA); \
          float xn = bi_n + inA + r * (bh_n + hnA); \
          xn = fminf(fmaxf(xn, -20.f), 20.f); \
          float tt = __expf(2.f * xn); \
          float n = (tt - 1.f) / (tt + 1.f); \
          outA = (1.f - z) * n + z * (oldA); } \
        { float r = sigmoid_f(bi_r + irB + bh_r + hrB); \
          float z = sigmoid_f(bi_z + izB + bh_z + hzB); \
          float xn = bi_n + inB + r * (bh_n + hnB); \
          xn = fminf(fmaxf(xn, -20.f), 20.f); \
          float tt = __expf(2.f * xn); \
          float n = (tt - 1.f) / (tt + 1.f); \
          outB = (1.f - z) * n + z * (oldB); } }
    GRUCH(0, hA0, hB0, QSEL(va0.x, va1.y, va2.z, va3.w), QSEL(vb0.x, vb1.y, vb2.z, vb3.w))
    GRUCH(1, hA1, hB1, QSEL(va0.y, va1.z, va2.w, va4.x), QSEL(vb0.y, vb1.z, vb2.w, vb4.x))
    GRUCH(2, hA2, hB2, QSEL(va0.z, va1.w, va3.x, va4.y), QSEL(vb0.z, vb1.w, vb3.x, vb4.y))
    GRUCH(3, hA3, hB3, QSEL(va0.w, va2.x, va3.y, va4.z), QSEL(vb0.w, vb2.x, vb3.y, vb4.z))
    GRUCH(4, hA4, hB4, QSEL(va1.x, va2.y, va3.z, va4.w), QSEL(vb1.x, vb2.y, vb3.z, vb4.w))
    #undef GRUCH

    // write h_out (5 contiguous floats per lane)
    {
        float* o0 = h_out + (size_t)e0 * NF + q * 5;
        float* o1 = h_out + (size_t)e1 * NF + q * 5;
        o0[0] = hA0; o0[1] = hA1; o0[2] = hA2; o0[3] = hA3; o0[4] = hA4;
        o1[0] = hB0; o1[1] = hB1; o1[2] = hB2; o1[3] = hB3; o1[4] = hB4;
    }

    if (WRITE_B) {
        // rebuild full h_new per lane via quad shfl, compute this lane's 8 B-chans
        int lane = threadIdx.x & 63;
        int qb = lane & ~3;
        float4 bbA0 = *(const float4*)&sb1v[ob];
        float4 bbA1 = *(const float4*)&sb1v[ob + 4];
        float4 bbB0 = bbA0, bbB1 = bbA1;
        #define BW(f, ql, r) { \
            float hfA = __shfl(hA##r, qb + (ql)); \
            float hfB = __shfl(hB##r, qb + (ql)); \
            const float4* w_ = (const float4*)&sW1b[(f)*32 + ob]; \
            float4 w0_ = w_[0], w1_ = w_[1]; \
            bbA0 = f4fma(hfA, w0_, bbA0); bbA1 = f4fma(hfA, w1_, bbA1); \
            bbB0 = f4fma(hfB, w0_, bbB0); bbB1 = f4fma(hfB, w1_, bbB1); }
        BW(0,0,0) BW(1,0,1) BW(2,0,2) BW(3,0,3) BW(4,0,4)
        BW(5,1,0) BW(6,1,1) BW(7,1,2) BW(8,1,3) BW(9,1,4)
        BW(10,2,0) BW(11,2,1) BW(12,2,2) BW(13,2,3) BW(14,2,4)
        BW(15,3,0) BW(16,3,1) BW(17,3,2) BW(18,3,3) BW(19,3,4)
        #undef BW
        uint4* bw = reinterpret_cast<uint4*>(Bw);
        bw[(size_t)e0 * 4 + q] = f8_to_h8(bbA0, bbA1);
        bw[(size_t)e1 * 4 + q] = f8_to_h8(bbB0, bbB1);
    }
}

__global__ void __launch_bounds__(256) kernel_readout(
    const float* __restrict__ h,
    const float* __restrict__ W1, const float* __restrict__ b1,
    const float* __restrict__ W2, const float* __restrict__ b2,
    const float* __restrict__ W3, const float* __restrict__ b3,
    float* __restrict__ out)
{
    __shared__ __align__(16) float sW1t[1280]; // transposed: (64,20)
    __shared__ float sb1[64];
    __shared__ __align__(16) float sW2[2048];  // (64,32)
    __shared__ __align__(16) float sb2v[32];
    __shared__ __align__(16) float sW3[32];
    __shared__ float sb3;
    for (int i = threadIdx.x; i < 1280; i += 256) {
        int f = i >> 6, o = i & 63;
        sW1t[o * 20 + f] = W1[i];
    }
    for (int i = threadIdx.x; i < 2048; i += 256) sW2[i] = W2[i];
    if (threadIdx.x < 64) sb1[threadIdx.x] = b1[threadIdx.x];
    else if (threadIdx.x >= 64 && threadIdx.x < 96) sb2v[threadIdx.x - 64] = b2[threadIdx.x - 64];
    else if (threadIdx.x >= 96 && threadIdx.x < 128) sW3[threadIdx.x - 96] = W3[threadIdx.x - 96];
    if (threadIdx.x == 128) sb3 = b3[0];
    __syncthreads();

    int e = blockIdx.x * 256 + threadIdx.x;
    const float4* hp = reinterpret_cast<const float4*>(h + (size_t)e * NF);
    float4 v0 = hp[0], v1 = hp[1], v2 = hp[2], v3 = hp[3], v4 = hp[4];

    const float4* b2p = reinterpret_cast<const float4*>(sb2v);
    float4 x20 = b2p[0], x21 = b2p[1], x22 = b2p[2], x23 = b2p[3],
           x24 = b2p[4], x25 = b2p[5], x26 = b2p[6], x27 = b2p[7];
    for (int o = 0; o < 64; o++) {
        float x1 = sb1[o] + dot20(v0, v1, v2, v3, v4, (const float4*)&sW1t[o * 20]);
        x1 = selu_f(x1);
        const float4* w = (const float4*)&sW2[o * 32];
        x20 = f4fma(x1, w[0], x20); x21 = f4fma(x1, w[1], x21);
        x22 = f4fma(x1, w[2], x22); x23 = f4fma(x1, w[3], x23);
        x24 = f4fma(x1, w[4], x24); x25 = f4fma(x1, w[5], x25);
        x26 = f4fma(x1, w[6], x26); x27 = f4fma(x1, w[7], x27);
    }
    const float4* w3p = reinterpret_cast<const float4*>(sW3);
    float acc = sb3;
    acc += dot4(selu4(x20), w3p[0]); acc += dot4(selu4(x21), w3p[1]);
    acc += dot4(selu4(x22), w3p[2]); acc += dot4(selu4(x23), w3p[3]);
    acc += dot4(selu4(x24), w3p[4]); acc += dot4(selu4(x25), w3p[5]);
    acc += dot4(selu4(x26), w3p[6]); acc += dot4(selu4(x27), w3p[7]);
    float sp = fmaxf(acc, 0.f) + log1pf(__expf(-fabsf(acc)));
    float w = sp + 0.1f;
    w = fminf(fmaxf(w, 0.1f), 10.f);
    out[e] = w;
}

extern "C" void kernel_launch(void* const* d_in, const int* in_sizes, int n_in,
                              void* d_out, int out_size, void* d_ws, size_t ws_size,
                              hipStream_t stream) {
    const float* edge_attr = (const float*)d_in[0];
    const float* msg_W1   = (const float*)d_in[1];
    const float* msg_b1   = (const float*)d_in[2];
    const float* msg_W2   = (const float*)d_in[3];
    const float* msg_b2   = (const float*)d_in[4];
    const float* gru_Wih  = (const float*)d_in[5];
    const float* gru_Whh  = (const float*)d_in[6];
    const float* gru_bih  = (const float*)d_in[7];
    const float* gru_bhh  = (const float*)d_in[8];
    const float* ro_W1    = (const float*)d_in[9];
    const float* ro_b1    = (const float*)d_in[10];
    const float* ro_W2    = (const float*)d_in[11];
    const float* ro_b2    = (const float*)d_in[12];
    const float* ro_W3    = (const float*)d_in[13];
    const float* ro_b3    = (const float*)d_in[14];
    const int* edge_index = (const int*)d_in[15];
    const int* dst = edge_index + E_EDGES;   // row 1 of (2,E)

    float*  h_ws = (float*)d_ws;                                  // E*20 f32
    __half* B0   = (__half*)(h_ws + (size_t)E_EDGES * NF);        // E*32 f16
    __half* B1   = B0 + (size_t)E_EDGES * 32;                     // E*32 f16

    dim3 block(256);
    dim3 gridB(E_EDGES / 256);
    dim3 gridS(E_EDGES * 2 / 256);     // 4 lanes per 2-edge pair

    kernel_B0<<<gridB, block, 0, stream>>>(edge_attr, msg_W1, msg_b1, B0);
    // step 0: edge_attr -> h_ws, B0 -> B1
    kernel_step<1><<<gridS, block, 0, stream>>>(edge_attr, h_ws, B0, B1, dst,
        msg_W1, msg_b1, msg_W2, msg_b2, gru_Wih, gru_Whh, gru_bih, gru_bhh);
    // step 1: h_ws in place, B1 -> B0
    kernel_step<1><<<gridS, block, 0, stream>>>(h_ws, h_ws, B1, B0, dst,
        msg_W1, msg_b1, msg_W2, msg_b2, gru_Wih, gru_Whh, gru_bih, gru_bhh);
    // step 2: B0 -> B1
    kernel_step<1><<<gridS, block, 0, stream>>>(h_ws, h_ws, B0, B1, dst,
        msg_W1, msg_b1, msg_W2, msg_b2, gru_Wih, gru_Whh, gru_bih, gru_bhh);
    // step 3: read B1, no B write
    kernel_step<0><<<gridS, block, 0, stream>>>(h_ws, h_ws, B1, B0, dst,
        msg_W1, msg_b1, msg_W2, msg_b2, gru_Wih, gru_Whh, gru_bih, gru_bhh);

    kernel_readout<<<gridB, block, 0, stream>>>(h_ws, ro_W1, ro_b1, ro_W2, ro_b2,
                                                ro_W3, ro_b3, (float*)d_out);
}

// Round 7
// 653.733 us; speedup vs baseline: 1.1128x; 1.1128x over previous
//
#include <hip/hip_runtime.h>
#include <hip/hip_fp16.h>

#define E_EDGES 320000
#define NF 20

__device__ __forceinline__ float selu_f(float x) {
    const float scale = 1.0507009873554805f;
    const float alpha = 1.6732632423543772f;
    // branchless: s*max(x,0) + s*a*(exp(min(x,0))-1)
    float p = fmaxf(x, 0.f);
    float m = fminf(x, 0.f);
    float e = __expf(m);
    return fmaf(scale, p, scale * alpha * (e - 1.f));
}
__device__ __forceinline__ float sigmoid_f(float x) {
    return 1.f / (1.f + __expf(-x));
}
__device__ __forceinline__ float4 f4z() { return make_float4(0.f, 0.f, 0.f, 0.f); }
__device__ __forceinline__ float4 f4fma(float a, float4 b, float4 c) {
    c.x = fmaf(a, b.x, c.x); c.y = fmaf(a, b.y, c.y);
    c.z = fmaf(a, b.z, c.z); c.w = fmaf(a, b.w, c.w); return c;
}
__device__ __forceinline__ float4 f4add(float4 a, float4 b) {
    return make_float4(a.x + b.x, a.y + b.y, a.z + b.z, a.w + b.w);
}
__device__ __forceinline__ float4 selu4(float4 x) {
    x.x = selu_f(x.x); x.y = selu_f(x.y); x.z = selu_f(x.z); x.w = selu_f(x.w); return x;
}
__device__ __forceinline__ float dot20(float4 a0, float4 a1, float4 a2, float4 a3, float4 a4,
                                       const float4* __restrict__ w) {
    float4 w0 = w[0], w1 = w[1], w2 = w[2], w3 = w[3], w4 = w[4];
    float r = a0.x * w0.x;
    r = fmaf(a0.y, w0.y, r); r = fmaf(a0.z, w0.z, r); r = fmaf(a0.w, w0.w, r);
    r = fmaf(a1.x, w1.x, r); r = fmaf(a1.y, w1.y, r); r = fmaf(a1.z, w1.z, r); r = fmaf(a1.w, w1.w, r);
    r = fmaf(a2.x, w2.x, r); r = fmaf(a2.y, w2.y, r); r = fmaf(a2.z, w2.z, r); r = fmaf(a2.w, w2.w, r);
    r = fmaf(a3.x, w3.x, r); r = fmaf(a3.y, w3.y, r); r = fmaf(a3.z, w3.z, r); r = fmaf(a3.w, w3.w, r);
    r = fmaf(a4.x, w4.x, r); r = fmaf(a4.y, w4.y, r); r = fmaf(a4.z, w4.z, r); r = fmaf(a4.w, w4.w, r);
    return r;
}
// one LDS row read serves BOTH edges
__device__ __forceinline__ void dot20_dual(const float4* __restrict__ w,
    float4 a0, float4 a1, float4 a2, float4 a3, float4 a4,
    float4 b0, float4 b1, float4 b2, float4 b3, float4 b4,
    float& r0, float& r1)
{
    float4 w0 = w[0], w1 = w[1], w2 = w[2], w3 = w[3], w4 = w[4];
    float r = a0.x * w0.x;
    r = fmaf(a0.y, w0.y, r); r = fmaf(a0.z, w0.z, r); r = fmaf(a0.w, w0.w, r);
    r = fmaf(a1.x, w1.x, r); r = fmaf(a1.y, w1.y, r); r = fmaf(a1.z, w1.z, r); r = fmaf(a1.w, w1.w, r);
    r = fmaf(a2.x, w2.x, r); r = fmaf(a2.y, w2.y, r); r = fmaf(a2.z, w2.z, r); r = fmaf(a2.w, w2.w, r);
    r = fmaf(a3.x, w3.x, r); r = fmaf(a3.y, w3.y, r); r = fmaf(a3.z, w3.z, r); r = fmaf(a3.w, w3.w, r);
    r = fmaf(a4.x, w4.x, r); r = fmaf(a4.y, w4.y, r); r = fmaf(a4.z, w4.z, r); r = fmaf(a4.w, w4.w, r);
    r0 = r;
    float s = b0.x * w0.x;
    s = fmaf(b0.y, w0.y, s); s = fmaf(b0.z, w0.z, s); s = fmaf(b0.w, w0.w, s);
    s = fmaf(b1.x, w1.x, s); s = fmaf(b1.y, w1.y, s); s = fmaf(b1.z, w1.z, s); s = fmaf(b1.w, w1.w, s);
    s = fmaf(b2.x, w2.x, s); s = fmaf(b2.y, w2.y, s); s = fmaf(b2.z, w2.z, s); s = fmaf(b2.w, w2.w, s);
    s = fmaf(b3.x, w3.x, s); s = fmaf(b3.y, w3.y, s); s = fmaf(b3.z, w3.z, s); s = fmaf(b3.w, w3.w, s);
    s = fmaf(b4.x, w4.x, s); s = fmaf(b4.y, w4.y, s); s = fmaf(b4.z, w4.z, s); s = fmaf(b4.w, w4.w, s);
    r1 = s;
}
__device__ __forceinline__ float dot4(float4 a, float4 b) {
    float r = a.x * b.x; r = fmaf(a.y, b.y, r); r = fmaf(a.z, b.z, r); r = fmaf(a.w, b.w, r);
    return r;
}
__device__ __forceinline__ void h8_to_f4x2(uint4 r, float4& lo, float4& hi) {
    float2 fa = __half22float2(__builtin_bit_cast(__half2, r.x));
    float2 fb = __half22float2(__builtin_bit_cast(__half2, r.y));
    float2 fc = __half22float2(__builtin_bit_cast(__half2, r.z));
    float2 fd = __half22float2(__builtin_bit_cast(__half2, r.w));
    lo = make_float4(fa.x, fa.y, fb.x, fb.y);
    hi = make_float4(fc.x, fc.y, fd.x, fd.y);
}
__device__ __forceinline__ uint4 f8_to_h8(float4 lo, float4 hi) {
    uint4 r;
    r.x = __builtin_bit_cast(unsigned, __floats2half2_rn(lo.x, lo.y));
    r.y = __builtin_bit_cast(unsigned, __floats2half2_rn(lo.z, lo.w));
    r.z = __builtin_bit_cast(unsigned, __floats2half2_rn(hi.x, hi.y));
    r.w = __builtin_bit_cast(unsigned, __floats2half2_rn(hi.z, hi.w));
    return r;
}

#define FOR20(X) \
  X(0, v0.x) X(1, v0.y) X(2, v0.z) X(3, v0.w) \
  X(4, v1.x) X(5, v1.y) X(6, v1.z) X(7, v1.w) \
  X(8, v2.x) X(9, v2.y) X(10, v2.z) X(11, v2.w) \
  X(12, v3.x) X(13, v3.y) X(14, v3.z) X(15, v3.w) \
  X(16, v4.x) X(17, v4.y) X(18, v4.z) X(19, v4.w)

#define FOR20_2(X) \
  X(0, va0.x, vb0.x) X(1, va0.y, vb0.y) X(2, va0.z, vb0.z) X(3, va0.w, vb0.w) \
  X(4, va1.x, vb1.x) X(5, va1.y, vb1.y) X(6, va1.z, vb1.z) X(7, va1.w, vb1.w) \
  X(8, va2.x, vb2.x) X(9, va2.y, vb2.y) X(10, va2.z, vb2.z) X(11, va2.w, vb2.w) \
  X(12, va3.x, vb3.x) X(13, va3.y, vb3.y) X(14, va3.z, vb3.z) X(15, va3.w, vb3.w) \
  X(16, va4.x, vb4.x) X(17, va4.y, vb4.y) X(18, va4.z, vb4.z) X(19, va4.w, vb4.w)

#define FOR8S2(X) \
  X(0, sa0.x, sb0.x) X(1, sa0.y, sb0.y) X(2, sa0.z, sb0.z) X(3, sa0.w, sb0.w) \
  X(4, sa1.x, sb1.x) X(5, sa1.y, sb1.y) X(6, sa1.z, sb1.z) X(7, sa1.w, sb1.w)

// B[e][o] = sum_f h[e][f] * W1[20+f][o] + b1[o], fp16 output
__global__ void __launch_bounds__(256) kernel_B0(
    const float* __restrict__ h, const float* __restrict__ W1,
    const float* __restrict__ b1, __half* __restrict__ B)
{
    __shared__ __align__(16) float sw[640];
    __shared__ __align__(16) float sbias[32];
    for (int i = threadIdx.x; i < 640; i += 256) sw[i] = W1[640 + i];
    if (threadIdx.x < 32) sbias[threadIdx.x] = b1[threadIdx.x];
    __syncthreads();
    int e = blockIdx.x * 256 + threadIdx.x;
    const float4* hp = reinterpret_cast<const float4*>(h + (size_t)e * NF);
    float4 v0 = hp[0], v1 = hp[1], v2 = hp[2], v3 = hp[3], v4 = hp[4];
    const float4* bi = reinterpret_cast<const float4*>(sbias);
    float4 c0 = bi[0], c1 = bi[1], c2 = bi[2], c3 = bi[3],
           c4 = bi[4], c5 = bi[5], c6 = bi[6], c7 = bi[7];
    #define BSTEP(f, hf) { float t_ = (hf); const float4* w_ = (const float4*)&sw[(f)*32]; \
        c0 = f4fma(t_, w_[0], c0); c1 = f4fma(t_, w_[1], c1); \
        c2 = f4fma(t_, w_[2], c2); c3 = f4fma(t_, w_[3], c3); \
        c4 = f4fma(t_, w_[4], c4); c5 = f4fma(t_, w_[5], c5); \
        c6 = f4fma(t_, w_[6], c6); c7 = f4fma(t_, w_[7], c7); }
    FOR20(BSTEP)
    #undef BSTEP
    uint4* Bp = reinterpret_cast<uint4*>(B + (size_t)e * 32);
    Bp[0] = f8_to_h8(c0, c1); Bp[1] = f8_to_h8(c2, c3);
    Bp[2] = f8_to_h8(c4, c5); Bp[3] = f8_to_h8(c6, c7);
}

// select this lane's old-h channel (i fixed, q runtime) — validated in R6
#define QSEL(x0, x1, x2, x3) (q < 2 ? (q == 0 ? (x0) : (x1)) : (q == 2 ? (x2) : (x3)))

// One step. 4 lanes/quad, 2 edges/thread, fp16 B gather. No fused B-write
// (R6 showed it costs occupancy: VGPR 64->120, step 132->152us — reverted).
__global__ void __launch_bounds__(256) kernel_step(
    const float* __restrict__ h_in, float* __restrict__ h_out,
    const __half* __restrict__ Br, const int* __restrict__ dst,
    const float* __restrict__ W1, const float* __restrict__ W2, const float* __restrict__ b2,
    const float* __restrict__ Wih, const float* __restrict__ Whh,
    const float* __restrict__ bih, const float* __restrict__ bhh)
{
    __shared__ __align__(16) float sW1[640];   // rows 0-19 of msg_W1 (20,32)
    __shared__ __align__(16) float sW2[640];   // (32,20)
    __shared__ __align__(16) float sb2v[20];
    __shared__ __align__(16) float sWih[1200]; // (60,20)
    __shared__ __align__(16) float sWhh[1200];
    __shared__ float sbih[60];
    __shared__ float sbhh[60];
    for (int i = threadIdx.x; i < 640; i += 256) { sW1[i] = W1[i]; sW2[i] = W2[i]; }
    for (int i = threadIdx.x; i < 1200; i += 256) { sWih[i] = Wih[i]; sWhh[i] = Whh[i]; }
    if (threadIdx.x < 20) sb2v[threadIdx.x] = b2[threadIdx.x];
    else if (threadIdx.x >= 64 && threadIdx.x < 124) sbih[threadIdx.x - 64] = bih[threadIdx.x - 64];
    else if (threadIdx.x >= 128 && threadIdx.x < 188) sbhh[threadIdx.x - 128] = bhh[threadIdx.x - 128];
    __syncthreads();

    int t = blockIdx.x * 256 + threadIdx.x;
    int p = t >> 2;
    int q = t & 3;
    int ob = q * 8;
    int e0 = p * 2, e1 = p * 2 + 1;

    int2 dd = *reinterpret_cast<const int2*>(dst + e0);
    int d0 = dd.x, d1 = dd.y;

    const float4* hp0 = reinterpret_cast<const float4*>(h_in + (size_t)e0 * NF);
    const float4* hp1 = reinterpret_cast<const float4*>(h_in + (size_t)e1 * NF);
    float4 va0 = hp0[0], va1 = hp0[1], va2 = hp0[2], va3 = hp0[3], va4 = hp0[4];
    float4 vb0 = hp1[0], vb1 = hp1[1], vb2 = hp1[2], vb3 = hp1[3], vb4 = hp1[4];

    // A slices for both edges (shared LDS weight reads)
    float4 aa0 = f4z(), aa1 = f4z(), ab0 = f4z(), ab1 = f4z();
    #define ASTEP2(f, h0, h1) { const float4* w_ = (const float4*)&sW1[(f)*32 + ob]; \
        float4 w0_ = w_[0], w1_ = w_[1]; \
        aa0 = f4fma((h0), w0_, aa0); aa1 = f4fma((h0), w1_, aa1); \
        ab0 = f4fma((h1), w0_, ab0); ab1 = f4fma((h1), w1_, ab1); }
    FOR20_2(ASTEP2)
    #undef ASTEP2

    // gather 16 fp16 rows per edge; 1 dwordx4 per row per edge = lane's 8 chans
    const uint4* Bp0 = reinterpret_cast<const uint4*>(Br) + (size_t)d0 * 64 + q;
    const uint4* Bp1 = reinterpret_cast<const uint4*>(Br) + (size_t)d1 * 64 + q;
    float4 sa0 = f4z(), sa1 = f4z(), sb0 = f4z(), sb1 = f4z();
    #pragma unroll 4
    for (int k = 0; k < 16; k++) {
        uint4 rA = Bp0[k * 4];
        uint4 rB = Bp1[k * 4];
        float4 loA, hiA, loB, hiB;
        h8_to_f4x2(rA, loA, hiA);
        h8_to_f4x2(rB, loB, hiB);
        sa0 = f4add(sa0, selu4(f4add(aa0, loA)));
        sa1 = f4add(sa1, selu4(f4add(aa1, hiA)));
        sb0 = f4add(sb0, selu4(f4add(ab0, loB)));
        sb1 = f4add(sb1, selu4(f4add(ab1, hiB)));
    }

    // partial agg (shared W2 rows)
    float4 ga0 = f4z(), ga1 = f4z(), ga2 = f4z(), ga3 = f4z(), ga4 = f4z();
    float4 gb0 = f4z(), gb1 = f4z(), gb2 = f4z(), gb3 = f4z(), gb4 = f4z();
    #define AGGS2(j, c0_, c1_) { const float4* w_ = (const float4*)&sW2[(ob + (j)) * 20]; \
        float4 w0_ = w_[0], w1_ = w_[1], w2_ = w_[2], w3_ = w_[3], w4_ = w_[4]; \
        float u_ = (c0_), v_ = (c1_); \
        ga0 = f4fma(u_, w0_, ga0); ga1 = f4fma(u_, w1_, ga1); ga2 = f4fma(u_, w2_, ga2); \
        ga3 = f4fma(u_, w3_, ga3); ga4 = f4fma(u_, w4_, ga4); \
        gb0 = f4fma(v_, w0_, gb0); gb1 = f4fma(v_, w1_, gb1); gb2 = f4fma(v_, w2_, gb2); \
        gb3 = f4fma(v_, w3_, gb3); gb4 = f4fma(v_, w4_, gb4); }
    FOR8S2(AGGS2)
    #undef AGGS2

    // quad butterfly
    #define BF1(r_, m_) r_.x += __shfl_xor(r_.x, m_); r_.y += __shfl_xor(r_.y, m_); \
                        r_.z += __shfl_xor(r_.z, m_); r_.w += __shfl_xor(r_.w, m_);
    #define BFLY(m_) BF1(ga0, m_) BF1(ga1, m_) BF1(ga2, m_) BF1(ga3, m_) BF1(ga4, m_) \
                     BF1(gb0, m_) BF1(gb1, m_) BF1(gb2, m_) BF1(gb3, m_) BF1(gb4, m_)
    BFLY(1)
    BFLY(2)
    #undef BFLY
    #undef BF1

    {
        const float4* b2p = reinterpret_cast<const float4*>(sb2v);
        float4 c0 = b2p[0], c1 = b2p[1], c2 = b2p[2], c3 = b2p[3], c4 = b2p[4];
        ga0 = f4fma(16.f, c0, ga0); ga1 = f4fma(16.f, c1, ga1); ga2 = f4fma(16.f, c2, ga2);
        ga3 = f4fma(16.f, c3, ga3); ga4 = f4fma(16.f, c4, ga4);
        gb0 = f4fma(16.f, c0, gb0); gb1 = f4fma(16.f, c1, gb1); gb2 = f4fma(16.f, c2, gb2);
        gb3 = f4fma(16.f, c3, gb3); gb4 = f4fma(16.f, c4, gb4);
    }

    // GRU: channels q*5+i, old-h from registers (QSEL), no h_in re-read
    float hA0, hA1, hA2, hA3, hA4, hB0, hB1, hB2, hB3, hB4;
    #define GRUCH(i, outA, outB, oldA, oldB) { \
        const int c = q * 5 + (i); \
        float irA, irB, izA, izB, inA, inB, hrA, hrB, hzA, hzB, hnA, hnB; \
        dot20_dual((const float4*)&sWih[c * 20],        ga0, ga1, ga2, ga3, ga4, gb0, gb1, gb2, gb3, gb4, irA, irB); \
        dot20_dual((const float4*)&sWih[(20 + c) * 20], ga0, ga1, ga2, ga3, ga4, gb0, gb1, gb2, gb3, gb4, izA, izB); \
        dot20_dual((const float4*)&sWih[(40 + c) * 20], ga0, ga1, ga2, ga3, ga4, gb0, gb1, gb2, gb3, gb4, inA, inB); \
        dot20_dual((const float4*)&sWhh[c * 20],        va0, va1, va2, va3, va4, vb0, vb1, vb2, vb3, vb4, hrA, hrB); \
        dot20_dual((const float4*)&sWhh[(20 + c) * 20], va0, va1, va2, va3, va4, vb0, vb1, vb2, vb3, vb4, hzA, hzB); \
        dot20_dual((const float4*)&sWhh[(40 + c) * 20], va0, va1, va2, va3, va4, vb0, vb1, vb2, vb3, vb4, hnA, hnB); \
        float bi_r = sbih[c], bi_z = sbih[20 + c], bi_n = sbih[40 + c]; \
        float bh_r = sbhh[c], bh_z = sbhh[20 + c], bh_n = sbhh[40 + c]; \
        { float r = sigmoid_f(bi_r + irA + bh_r + hrA); \
          float z = sigmoid_f(bi_z + izA + bh_z + hzA); \
          float xn = bi_n + inA + r * (bh_n + hnA); \
          xn = fminf(fmaxf(xn, -20.f), 20.f); \
          float tt = __expf(2.f * xn); \
          float n = (tt - 1.f) / (tt + 1.f); \
          outA = (1.f - z) * n + z * (oldA); } \
        { float r = sigmoid_f(bi_r + irB + bh_r + hrB); \
          float z = sigmoid_f(bi_z + izB + bh_z + hzB); \
          float xn = bi_n + inB + r * (bh_n + hnB); \
          xn = fminf(fmaxf(xn, -20.f), 20.f); \
          float tt = __expf(2.f * xn); \
          float n = (tt - 1.f) / (tt + 1.f); \
          outB = (1.f - z) * n + z * (oldB); } }
    GRUCH(0, hA0, hB0, QSEL(va0.x, va1.y, va2.z, va3.w), QSEL(vb0.x, vb1.y, vb2.z, vb3.w))
    GRUCH(1, hA1, hB1, QSEL(va0.y, va1.z, va2.w, va4.x), QSEL(vb0.y, vb1.z, vb2.w, vb4.x))
    GRUCH(2, hA2, hB2, QSEL(va0.z, va1.w, va3.x, va4.y), QSEL(vb0.z, vb1.w, vb3.x, vb4.y))
    GRUCH(3, hA3, hB3, QSEL(va0.w, va2.x, va3.y, va4.z), QSEL(vb0.w, vb2.x, vb3.y, vb4.z))
    GRUCH(4, hA4, hB4, QSEL(va1.x, va2.y, va3.z, va4.w), QSEL(vb1.x, vb2.y, vb3.z, vb4.w))
    #undef GRUCH

    // write h_out (5 contiguous floats per lane; quad covers the 20-float row)
    {
        float* o0 = h_out + (size_t)e0 * NF + q * 5;
        float* o1 = h_out + (size_t)e1 * NF + q * 5;
        o0[0] = hA0; o0[1] = hA1; o0[2] = hA2; o0[3] = hA3; o0[4] = hA4;
        o1[0] = hB0; o1[1] = hB1; o1[2] = hB2; o1[3] = hB3; o1[4] = hB4;
    }
}

__global__ void __launch_bounds__(256) kernel_readout(
    const float* __restrict__ h,
    const float* __restrict__ W1, const float* __restrict__ b1,
    const float* __restrict__ W2, const float* __restrict__ b2,
    const float* __restrict__ W3, const float* __restrict__ b3,
    float* __restrict__ out)
{
    __shared__ __align__(16) float sW1t[1280]; // transposed: (64,20)
    __shared__ float sb1[64];
    __shared__ __align__(16) float sW2[2048];  // (64,32)
    __shared__ __align__(16) float sb2v[32];
    __shared__ __align__(16) float sW3[32];
    __shared__ float sb3;
    for (int i = threadIdx.x; i < 1280; i += 256) {
        int f = i >> 6, o = i & 63;
        sW1t[o * 20 + f] = W1[i];
    }
    for (int i = threadIdx.x; i < 2048; i += 256) sW2[i] = W2[i];
    if (threadIdx.x < 64) sb1[threadIdx.x] = b1[threadIdx.x];
    else if (threadIdx.x >= 64 && threadIdx.x < 96) sb2v[threadIdx.x - 64] = b2[threadIdx.x - 64];
    else if (threadIdx.x >= 96 && threadIdx.x < 128) sW3[threadIdx.x - 96] = W3[threadIdx.x - 96];
    if (threadIdx.x == 128) sb3 = b3[0];
    __syncthreads();

    int e = blockIdx.x * 256 + threadIdx.x;
    const float4* hp = reinterpret_cast<const float4*>(h + (size_t)e * NF);
    float4 v0 = hp[0], v1 = hp[1], v2 = hp[2], v3 = hp[3], v4 = hp[4];

    const float4* b2p = reinterpret_cast<const float4*>(sb2v);
    float4 x20 = b2p[0], x21 = b2p[1], x22 = b2p[2], x23 = b2p[3],
           x24 = b2p[4], x25 = b2p[5], x26 = b2p[6], x27 = b2p[7];
    for (int o = 0; o < 64; o++) {
        float x1 = sb1[o] + dot20(v0, v1, v2, v3, v4, (const float4*)&sW1t[o * 20]);
        x1 = selu_f(x1);
        const float4* w = (const float4*)&sW2[o * 32];
        x20 = f4fma(x1, w[0], x20); x21 = f4fma(x1, w[1], x21);
        x22 = f4fma(x1, w[2], x22); x23 = f4fma(x1, w[3], x23);
        x24 = f4fma(x1, w[4], x24); x25 = f4fma(x1, w[5], x25);
        x26 = f4fma(x1, w[6], x26); x27 = f4fma(x1, w[7], x27);
    }
    const float4* w3p = reinterpret_cast<const float4*>(sW3);
    float acc = sb3;
    acc += dot4(selu4(x20), w3p[0]); acc += dot4(selu4(x21), w3p[1]);
    acc += dot4(selu4(x22), w3p[2]); acc += dot4(selu4(x23), w3p[3]);
    acc += dot4(selu4(x24), w3p[4]); acc += dot4(selu4(x25), w3p[5]);
    acc += dot4(selu4(x26), w3p[6]); acc += dot4(selu4(x27), w3p[7]);
    float sp = fmaxf(acc, 0.f) + log1pf(__expf(-fabsf(acc)));
    float w = sp + 0.1f;
    w = fminf(fmaxf(w, 0.1f), 10.f);
    out[e] = w;
}

extern "C" void kernel_launch(void* const* d_in, const int* in_sizes, int n_in,
                              void* d_out, int out_size, void* d_ws, size_t ws_size,
                              hipStream_t stream) {
    const float* edge_attr = (const float*)d_in[0];
    const float* msg_W1   = (const float*)d_in[1];
    const float* msg_b1   = (const float*)d_in[2];
    const float* msg_W2   = (const float*)d_in[3];
    const float* msg_b2   = (const float*)d_in[4];
    const float* gru_Wih  = (const float*)d_in[5];
    const float* gru_Whh  = (const float*)d_in[6];
    const float* gru_bih  = (const float*)d_in[7];
    const float* gru_bhh  = (const float*)d_in[8];
    const float* ro_W1    = (const float*)d_in[9];
    const float* ro_b1    = (const float*)d_in[10];
    const float* ro_W2    = (const float*)d_in[11];
    const float* ro_b2    = (const float*)d_in[12];
    const float* ro_W3    = (const float*)d_in[13];
    const float* ro_b3    = (const float*)d_in[14];
    const int* edge_index = (const int*)d_in[15];
    const int* dst = edge_index + E_EDGES;   // row 1 of (2,E)

    float*  h_ws = (float*)d_ws;                                  // E*20 f32
    __half* Bt   = (__half*)(h_ws + (size_t)E_EDGES * NF);        // E*32 f16

    dim3 block(256);
    dim3 gridB(E_EDGES / 256);
    dim3 gridS(E_EDGES * 2 / 256);     // 4 lanes per 2-edge pair

    const float* hin = edge_attr;
    for (int s = 0; s < 4; s++) {
        kernel_B0<<<gridB, block, 0, stream>>>(hin, msg_W1, msg_b1, Bt);
        kernel_step<<<gridS, block, 0, stream>>>(hin, h_ws, Bt, dst,
            msg_W1, msg_W2, msg_b2, gru_Wih, gru_Whh, gru_bih, gru_bhh);
        hin = h_ws;
    }
    kernel_readout<<<gridB, block, 0, stream>>>(h_ws, ro_W1, ro_b1, ro_W2, ro_b2,
                                                ro_W3, ro_b3, (float*)d_out);
}

// Round 8
// 614.018 us; speedup vs baseline: 1.1848x; 1.0647x over previous
//
#include <hip/hip_runtime.h>
#include <hip/hip_fp16.h>

#define E_EDGES 320000
#define NF 20

__device__ __forceinline__ float selu_f(float x) {
    const float scale = 1.0507009873554805f;
    const float alpha = 1.6732632423543772f;
    float p = fmaxf(x, 0.f);
    float m = fminf(x, 0.f);
    float e = __expf(m);
    return fmaf(scale, p, scale * alpha * (e - 1.f));
}
__device__ __forceinline__ float sigmoid_f(float x) {
    return 1.f / (1.f + __expf(-x));
}
__device__ __forceinline__ float4 f4z() { return make_float4(0.f, 0.f, 0.f, 0.f); }
__device__ __forceinline__ float4 f4fma(float a, float4 b, float4 c) {
    c.x = fmaf(a, b.x, c.x); c.y = fmaf(a, b.y, c.y);
    c.z = fmaf(a, b.z, c.z); c.w = fmaf(a, b.w, c.w); return c;
}
__device__ __forceinline__ float4 f4add(float4 a, float4 b) {
    return make_float4(a.x + b.x, a.y + b.y, a.z + b.z, a.w + b.w);
}
__device__ __forceinline__ float4 selu4(float4 x) {
    x.x = selu_f(x.x); x.y = selu_f(x.y); x.z = selu_f(x.z); x.w = selu_f(x.w); return x;
}
__device__ __forceinline__ float dot20(float4 a0, float4 a1, float4 a2, float4 a3, float4 a4,
                                       const float4* __restrict__ w) {
    float4 w0 = w[0], w1 = w[1], w2 = w[2], w3 = w[3], w4 = w[4];
    float r = a0.x * w0.x;
    r = fmaf(a0.y, w0.y, r); r = fmaf(a0.z, w0.z, r); r = fmaf(a0.w, w0.w, r);
    r = fmaf(a1.x, w1.x, r); r = fmaf(a1.y, w1.y, r); r = fmaf(a1.z, w1.z, r); r = fmaf(a1.w, w1.w, r);
    r = fmaf(a2.x, w2.x, r); r = fmaf(a2.y, w2.y, r); r = fmaf(a2.z, w2.z, r); r = fmaf(a2.w, w2.w, r);
    r = fmaf(a3.x, w3.x, r); r = fmaf(a3.y, w3.y, r); r = fmaf(a3.z, w3.z, r); r = fmaf(a3.w, w3.w, r);
    r = fmaf(a4.x, w4.x, r); r = fmaf(a4.y, w4.y, r); r = fmaf(a4.z, w4.z, r); r = fmaf(a4.w, w4.w, r);
    return r;
}
// one LDS row read serves BOTH edges
__device__ __forceinline__ void dot20_dual(const float4* __restrict__ w,
    float4 a0, float4 a1, float4 a2, float4 a3, float4 a4,
    float4 b0, float4 b1, float4 b2, float4 b3, float4 b4,
    float& r0, float& r1)
{
    float4 w0 = w[0], w1 = w[1], w2 = w[2], w3 = w[3], w4 = w[4];
    float r = a0.x * w0.x;
    r = fmaf(a0.y, w0.y, r); r = fmaf(a0.z, w0.z, r); r = fmaf(a0.w, w0.w, r);
    r = fmaf(a1.x, w1.x, r); r = fmaf(a1.y, w1.y, r); r = fmaf(a1.z, w1.z, r); r = fmaf(a1.w, w1.w, r);
    r = fmaf(a2.x, w2.x, r); r = fmaf(a2.y, w2.y, r); r = fmaf(a2.z, w2.z, r); r = fmaf(a2.w, w2.w, r);
    r = fmaf(a3.x, w3.x, r); r = fmaf(a3.y, w3.y, r); r = fmaf(a3.z, w3.z, r); r = fmaf(a3.w, w3.w, r);
    r = fmaf(a4.x, w4.x, r); r = fmaf(a4.y, w4.y, r); r = fmaf(a4.z, w4.z, r); r = fmaf(a4.w, w4.w, r);
    r0 = r;
    float s = b0.x * w0.x;
    s = fmaf(b0.y, w0.y, s); s = fmaf(b0.z, w0.z, s); s = fmaf(b0.w, w0.w, s);
    s = fmaf(b1.x, w1.x, s); s = fmaf(b1.y, w1.y, s); s = fmaf(b1.z, w1.z, s); s = fmaf(b1.w, w1.w, s);
    s = fmaf(b2.x, w2.x, s); s = fmaf(b2.y, w2.y, s); s = fmaf(b2.z, w2.z, s); s = fmaf(b2.w, w2.w, s);
    s = fmaf(b3.x, w3.x, s); s = fmaf(b3.y, w3.y, s); s = fmaf(b3.z, w3.z, s); s = fmaf(b3.w, w3.w, s);
    s = fmaf(b4.x, w4.x, s); s = fmaf(b4.y, w4.y, s); s = fmaf(b4.z, w4.z, s); s = fmaf(b4.w, w4.w, s);
    r1 = s;
}
__device__ __forceinline__ float dot4(float4 a, float4 b) {
    float r = a.x * b.x; r = fmaf(a.y, b.y, r); r = fmaf(a.z, b.z, r); r = fmaf(a.w, b.w, r);
    return r;
}
__device__ __forceinline__ void h8_to_f4x2(uint4 r, float4& lo, float4& hi) {
    float2 fa = __half22float2(__builtin_bit_cast(__half2, r.x));
    float2 fb = __half22float2(__builtin_bit_cast(__half2, r.y));
    float2 fc = __half22float2(__builtin_bit_cast(__half2, r.z));
    float2 fd = __half22float2(__builtin_bit_cast(__half2, r.w));
    lo = make_float4(fa.x, fa.y, fb.x, fb.y);
    hi = make_float4(fc.x, fc.y, fd.x, fd.y);
}
__device__ __forceinline__ uint4 f8_to_h8(float4 lo, float4 hi) {
    uint4 r;
    r.x = __builtin_bit_cast(unsigned, __floats2half2_rn(lo.x, lo.y));
    r.y = __builtin_bit_cast(unsigned, __floats2half2_rn(lo.z, lo.w));
    r.z = __builtin_bit_cast(unsigned, __floats2half2_rn(hi.x, hi.y));
    r.w = __builtin_bit_cast(unsigned, __floats2half2_rn(hi.z, hi.w));
    return r;
}

#define FOR20(X) \
  X(0, v0.x) X(1, v0.y) X(2, v0.z) X(3, v0.w) \
  X(4, v1.x) X(5, v1.y) X(6, v1.z) X(7, v1.w) \
  X(8, v2.x) X(9, v2.y) X(10, v2.z) X(11, v2.w) \
  X(12, v3.x) X(13, v3.y) X(14, v3.z) X(15, v3.w) \
  X(16, v4.x) X(17, v4.y) X(18, v4.z) X(19, v4.w)

#define FOR20_2(X) \
  X(0, va0.x, vb0.x) X(1, va0.y, vb0.y) X(2, va0.z, vb0.z) X(3, va0.w, vb0.w) \
  X(4, va1.x, vb1.x) X(5, va1.y, vb1.y) X(6, va1.z, vb1.z) X(7, va1.w, vb1.w) \
  X(8, va2.x, vb2.x) X(9, va2.y, vb2.y) X(10, va2.z, vb2.z) X(11, va2.w, vb2.w) \
  X(12, va3.x, vb3.x) X(13, va3.y, vb3.y) X(14, va3.z, vb3.z) X(15, va3.w, vb3.w) \
  X(16, va4.x, vb4.x) X(17, va4.y, vb4.y) X(18, va4.z, vb4.z) X(19, va4.w, vb4.w)

#define FOR8S2(X) \
  X(0, sa0.x, sb0.x) X(1, sa0.y, sb0.y) X(2, sa0.z, sb0.z) X(3, sa0.w, sb0.w) \
  X(4, sa1.x, sb1.x) X(5, sa1.y, sb1.y) X(6, sa1.z, sb1.z) X(7, sa1.w, sb1.w)

// B[e][o] = sum_f h[e][f] * W1[20+f][o] + b1[o], fp16 output
__global__ void __launch_bounds__(256) kernel_B0(
    const float* __restrict__ h, const float* __restrict__ W1,
    const float* __restrict__ b1, __half* __restrict__ B)
{
    __shared__ __align__(16) float sw[640];
    __shared__ __align__(16) float sbias[32];
    for (int i = threadIdx.x; i < 640; i += 256) sw[i] = W1[640 + i];
    if (threadIdx.x < 32) sbias[threadIdx.x] = b1[threadIdx.x];
    __syncthreads();
    int e = blockIdx.x * 256 + threadIdx.x;
    const float4* hp = reinterpret_cast<const float4*>(h + (size_t)e * NF);
    float4 v0 = hp[0], v1 = hp[1], v2 = hp[2], v3 = hp[3], v4 = hp[4];
    const float4* bi = reinterpret_cast<const float4*>(sbias);
    float4 c0 = bi[0], c1 = bi[1], c2 = bi[2], c3 = bi[3],
           c4 = bi[4], c5 = bi[5], c6 = bi[6], c7 = bi[7];
    #define BSTEP(f, hf) { float t_ = (hf); const float4* w_ = (const float4*)&sw[(f)*32]; \
        c0 = f4fma(t_, w_[0], c0); c1 = f4fma(t_, w_[1], c1); \
        c2 = f4fma(t_, w_[2], c2); c3 = f4fma(t_, w_[3], c3); \
        c4 = f4fma(t_, w_[4], c4); c5 = f4fma(t_, w_[5], c5); \
        c6 = f4fma(t_, w_[6], c6); c7 = f4fma(t_, w_[7], c7); }
    FOR20(BSTEP)
    #undef BSTEP
    uint4* Bp = reinterpret_cast<uint4*>(B + (size_t)e * 32);
    Bp[0] = f8_to_h8(c0, c1); Bp[1] = f8_to_h8(c2, c3);
    Bp[2] = f8_to_h8(c4, c5); Bp[3] = f8_to_h8(c6, c7);
}

// One step. 4 lanes/quad, 2 edges/thread, fp16 B gather.
// GRU is a ROLLED loop (dynamic c indexes LDS only, old-h re-read from
// global L1): R5 measured VGPR=64 / 8 waves/SIMD with this shape, vs 120 /
// 4 waves for the unrolled QSEL version (R7). Occupancy is the lever here.
__global__ void __launch_bounds__(256) kernel_step(
    const float* __restrict__ h_in, float* __restrict__ h_out,
    const __half* __restrict__ Br, const int* __restrict__ dst,
    const float* __restrict__ W1, const float* __restrict__ W2, const float* __restrict__ b2,
    const float* __restrict__ Wih, const float* __restrict__ Whh,
    const float* __restrict__ bih, const float* __restrict__ bhh)
{
    __shared__ __align__(16) float sW1[640];   // rows 0-19 of msg_W1 (20,32)
    __shared__ __align__(16) float sW2[640];   // (32,20)
    __shared__ __align__(16) float sb2v[20];
    __shared__ __align__(16) float sWih[1200]; // (60,20)
    __shared__ __align__(16) float sWhh[1200];
    __shared__ float sbih[60];
    __shared__ float sbhh[60];
    for (int i = threadIdx.x; i < 640; i += 256) { sW1[i] = W1[i]; sW2[i] = W2[i]; }
    for (int i = threadIdx.x; i < 1200; i += 256) { sWih[i] = Wih[i]; sWhh[i] = Whh[i]; }
    if (threadIdx.x < 20) sb2v[threadIdx.x] = b2[threadIdx.x];
    else if (threadIdx.x >= 64 && threadIdx.x < 124) sbih[threadIdx.x - 64] = bih[threadIdx.x - 64];
    else if (threadIdx.x >= 128 && threadIdx.x < 188) sbhh[threadIdx.x - 128] = bhh[threadIdx.x - 128];
    __syncthreads();

    int t = blockIdx.x * 256 + threadIdx.x;
    int p = t >> 2;
    int q = t & 3;
    int ob = q * 8;
    int e0 = p * 2, e1 = p * 2 + 1;

    int2 dd = *reinterpret_cast<const int2*>(dst + e0);
    int d0 = dd.x, d1 = dd.y;

    const float4* hp0 = reinterpret_cast<const float4*>(h_in + (size_t)e0 * NF);
    const float4* hp1 = reinterpret_cast<const float4*>(h_in + (size_t)e1 * NF);
    float4 va0 = hp0[0], va1 = hp0[1], va2 = hp0[2], va3 = hp0[3], va4 = hp0[4];
    float4 vb0 = hp1[0], vb1 = hp1[1], vb2 = hp1[2], vb3 = hp1[3], vb4 = hp1[4];

    // A slices for both edges (shared LDS weight reads)
    float4 aa0 = f4z(), aa1 = f4z(), ab0 = f4z(), ab1 = f4z();
    #define ASTEP2(f, h0, h1) { const float4* w_ = (const float4*)&sW1[(f)*32 + ob]; \
        float4 w0_ = w_[0], w1_ = w_[1]; \
        aa0 = f4fma((h0), w0_, aa0); aa1 = f4fma((h0), w1_, aa1); \
        ab0 = f4fma((h1), w0_, ab0); ab1 = f4fma((h1), w1_, ab1); }
    FOR20_2(ASTEP2)
    #undef ASTEP2

    // gather 16 fp16 rows per edge; 1 dwordx4 per row per edge = lane's 8 chans
    const uint4* Bp0 = reinterpret_cast<const uint4*>(Br) + (size_t)d0 * 64 + q;
    const uint4* Bp1 = reinterpret_cast<const uint4*>(Br) + (size_t)d1 * 64 + q;
    float4 sa0 = f4z(), sa1 = f4z(), sb0 = f4z(), sb1 = f4z();
    #pragma unroll 4
    for (int k = 0; k < 16; k++) {
        uint4 rA = Bp0[k * 4];
        uint4 rB = Bp1[k * 4];
        float4 loA, hiA, loB, hiB;
        h8_to_f4x2(rA, loA, hiA);
        h8_to_f4x2(rB, loB, hiB);
        sa0 = f4add(sa0, selu4(f4add(aa0, loA)));
        sa1 = f4add(sa1, selu4(f4add(aa1, hiA)));
        sb0 = f4add(sb0, selu4(f4add(ab0, loB)));
        sb1 = f4add(sb1, selu4(f4add(ab1, hiB)));
    }

    // partial agg (shared W2 rows)
    float4 ga0 = f4z(), ga1 = f4z(), ga2 = f4z(), ga3 = f4z(), ga4 = f4z();
    float4 gb0 = f4z(), gb1 = f4z(), gb2 = f4z(), gb3 = f4z(), gb4 = f4z();
    #define AGGS2(j, c0_, c1_) { const float4* w_ = (const float4*)&sW2[(ob + (j)) * 20]; \
        float4 w0_ = w_[0], w1_ = w_[1], w2_ = w_[2], w3_ = w_[3], w4_ = w_[4]; \
        float u_ = (c0_), v_ = (c1_); \
        ga0 = f4fma(u_, w0_, ga0); ga1 = f4fma(u_, w1_, ga1); ga2 = f4fma(u_, w2_, ga2); \
        ga3 = f4fma(u_, w3_, ga3); ga4 = f4fma(u_, w4_, ga4); \
        gb0 = f4fma(v_, w0_, gb0); gb1 = f4fma(v_, w1_, gb1); gb2 = f4fma(v_, w2_, gb2); \
        gb3 = f4fma(v_, w3_, gb3); gb4 = f4fma(v_, w4_, gb4); }
    FOR8S2(AGGS2)
    #undef AGGS2

    // quad butterfly
    #define BF1(r_, m_) r_.x += __shfl_xor(r_.x, m_); r_.y += __shfl_xor(r_.y, m_); \
                        r_.z += __shfl_xor(r_.z, m_); r_.w += __shfl_xor(r_.w, m_);
    #define BFLY(m_) BF1(ga0, m_) BF1(ga1, m_) BF1(ga2, m_) BF1(ga3, m_) BF1(ga4, m_) \
                     BF1(gb0, m_) BF1(gb1, m_) BF1(gb2, m_) BF1(gb3, m_) BF1(gb4, m_)
    BFLY(1)
    BFLY(2)
    #undef BFLY
    #undef BF1

    {
        const float4* b2p = reinterpret_cast<const float4*>(sb2v);
        float4 c0 = b2p[0], c1 = b2p[1], c2 = b2p[2], c3 = b2p[3], c4 = b2p[4];
        ga0 = f4fma(16.f, c0, ga0); ga1 = f4fma(16.f, c1, ga1); ga2 = f4fma(16.f, c2, ga2);
        ga3 = f4fma(16.f, c3, ga3); ga4 = f4fma(16.f, c4, ga4);
        gb0 = f4fma(16.f, c0, gb0); gb1 = f4fma(16.f, c1, gb1); gb2 = f4fma(16.f, c2, gb2);
        gb3 = f4fma(16.f, c3, gb3); gb4 = f4fma(16.f, c4, gb4);
    }

    // GRU: 5 channels per lane, ROLLED loop (dynamic index hits LDS only).
    // old-h scalar re-read is L1-hot; in-place safe: each lane reads/writes
    // only its own channels, read-before-write in program order.
    for (int i = 0; i < 5; i++) {
        int c = q * 5 + i;
        float ir0, ir1, iz0, iz1, in0, in1, hr0, hr1, hz0, hz1, hn0, hn1;
        dot20_dual((const float4*)&sWih[c * 20],        ga0, ga1, ga2, ga3, ga4,
                   gb0, gb1, gb2, gb3, gb4, ir0, ir1);
        dot20_dual((const float4*)&sWih[(20 + c) * 20], ga0, ga1, ga2, ga3, ga4,
                   gb0, gb1, gb2, gb3, gb4, iz0, iz1);
        dot20_dual((const float4*)&sWih[(40 + c) * 20], ga0, ga1, ga2, ga3, ga4,
                   gb0, gb1, gb2, gb3, gb4, in0, in1);
        dot20_dual((const float4*)&sWhh[c * 20],        va0, va1, va2, va3, va4,
                   vb0, vb1, vb2, vb3, vb4, hr0, hr1);
        dot20_dual((const float4*)&sWhh[(20 + c) * 20], va0, va1, va2, va3, va4,
                   vb0, vb1, vb2, vb3, vb4, hz0, hz1);
        dot20_dual((const float4*)&sWhh[(40 + c) * 20], va0, va1, va2, va3, va4,
                   vb0, vb1, vb2, vb3, vb4, hn0, hn1);
        float bi_r = sbih[c], bi_z = sbih[20 + c], bi_n = sbih[40 + c];
        float bh_r = sbhh[c], bh_z = sbhh[20 + c], bh_n = sbhh[40 + c];
        {
            float r = sigmoid_f(bi_r + ir0 + bh_r + hr0);
            float z = sigmoid_f(bi_z + iz0 + bh_z + hz0);
            float xn = bi_n + in0 + r * (bh_n + hn0);
            xn = fminf(fmaxf(xn, -20.f), 20.f);
            float tt = __expf(2.f * xn);
            float n = (tt - 1.f) / (tt + 1.f);
            float hc = h_in[(size_t)e0 * NF + c];
            h_out[(size_t)e0 * NF + c] = (1.f - z) * n + z * hc;
        }
        {
            float r = sigmoid_f(bi_r + ir1 + bh_r + hr1);
            float z = sigmoid_f(bi_z + iz1 + bh_z + hz1);
            float xn = bi_n + in1 + r * (bh_n + hn1);
            xn = fminf(fmaxf(xn, -20.f), 20.f);
            float tt = __expf(2.f * xn);
            float n = (tt - 1.f) / (tt + 1.f);
            float hc = h_in[(size_t)e1 * NF + c];
            h_out[(size_t)e1 * NF + c] = (1.f - z) * n + z * hc;
        }
    }
}

__global__ void __launch_bounds__(256) kernel_readout(
    const float* __restrict__ h,
    const float* __restrict__ W1, const float* __restrict__ b1,
    const float* __restrict__ W2, const float* __restrict__ b2,
    const float* __restrict__ W3, const float* __restrict__ b3,
    float* __restrict__ out)
{
    __shared__ __align__(16) float sW1t[1280]; // transposed: (64,20)
    __shared__ float sb1[64];
    __shared__ __align__(16) float sW2[2048];  // (64,32)
    __shared__ __align__(16) float sb2v[32];
    __shared__ __align__(16) float sW3[32];
    __shared__ float sb3;
    for (int i = threadIdx.x; i < 1280; i += 256) {
        int f = i >> 6, o = i & 63;
        sW1t[o * 20 + f] = W1[i];
    }
    for (int i = threadIdx.x; i < 2048; i += 256) sW2[i] = W2[i];
    if (threadIdx.x < 64) sb1[threadIdx.x] = b1[threadIdx.x];
    else if (threadIdx.x >= 64 && threadIdx.x < 96) sb2v[threadIdx.x - 64] = b2[threadIdx.x - 64];
    else if (threadIdx.x >= 96 && threadIdx.x < 128) sW3[threadIdx.x - 96] = W3[threadIdx.x - 96];
    if (threadIdx.x == 128) sb3 = b3[0];
    __syncthreads();

    int e = blockIdx.x * 256 + threadIdx.x;
    const float4* hp = reinterpret_cast<const float4*>(h + (size_t)e * NF);
    float4 v0 = hp[0], v1 = hp[1], v2 = hp[2], v3 = hp[3], v4 = hp[4];

    const float4* b2p = reinterpret_cast<const float4*>(sb2v);
    float4 x20 = b2p[0], x21 = b2p[1], x22 = b2p[2], x23 = b2p[3],
           x24 = b2p[4], x25 = b2p[5], x26 = b2p[6], x27 = b2p[7];
    for (int o = 0; o < 64; o++) {
        float x1 = sb1[o] + dot20(v0, v1, v2, v3, v4, (const float4*)&sW1t[o * 20]);
        x1 = selu_f(x1);
        const float4* w = (const float4*)&sW2[o * 32];
        x20 = f4fma(x1, w[0], x20); x21 = f4fma(x1, w[1], x21);
        x22 = f4fma(x1, w[2], x22); x23 = f4fma(x1, w[3], x23);
        x24 = f4fma(x1, w[4], x24); x25 = f4fma(x1, w[5], x25);
        x26 = f4fma(x1, w[6], x26); x27 = f4fma(x1, w[7], x27);
    }
    const float4* w3p = reinterpret_cast<const float4*>(sW3);
    float acc = sb3;
    acc += dot4(selu4(x20), w3p[0]); acc += dot4(selu4(x21), w3p[1]);
    acc += dot4(selu4(x22), w3p[2]); acc += dot4(selu4(x23), w3p[3]);
    acc += dot4(selu4(x24), w3p[4]); acc += dot4(selu4(x25), w3p[5]);
    acc += dot4(selu4(x26), w3p[6]); acc += dot4(selu4(x27), w3p[7]);
    float sp = fmaxf(acc, 0.f) + log1pf(__expf(-fabsf(acc)));
    float w = sp + 0.1f;
    w = fminf(fmaxf(w, 0.1f), 10.f);
    out[e] = w;
}

extern "C" void kernel_launch(void* const* d_in, const int* in_sizes, int n_in,
                              void* d_out, int out_size, void* d_ws, size_t ws_size,
                              hipStream_t stream) {
    const float* edge_attr = (const float*)d_in[0];
    const float* msg_W1   = (const float*)d_in[1];
    const float* msg_b1   = (const float*)d_in[2];
    const float* msg_W2   = (const float*)d_in[3];
    const float* msg_b2   = (const float*)d_in[4];
    const float* gru_Wih  = (const float*)d_in[5];
    const float* gru_Whh  = (const float*)d_in[6];
    const float* gru_bih  = (const float*)d_in[7];
    const float* gru_bhh  = (const float*)d_in[8];
    const float* ro_W1    = (const float*)d_in[9];
    const float* ro_b1    = (const float*)d_in[10];
    const float* ro_W2    = (const float*)d_in[11];
    const float* ro_b2    = (const float*)d_in[12];
    const float* ro_W3    = (const float*)d_in[13];
    const float* ro_b3    = (const float*)d_in[14];
    const int* edge_index = (const int*)d_in[15];
    const int* dst = edge_index + E_EDGES;   // row 1 of (2,E)

    float*  h_ws = (float*)d_ws;                                  // E*20 f32
    __half* Bt   = (__half*)(h_ws + (size_t)E_EDGES * NF);        // E*32 f16

    dim3 block(256);
    dim3 gridB(E_EDGES / 256);
    dim3 gridS(E_EDGES * 2 / 256);     // 4 lanes per 2-edge pair

    const float* hin = edge_attr;
    for (int s = 0; s < 4; s++) {
        kernel_B0<<<gridB, block, 0, stream>>>(hin, msg_W1, msg_b1, Bt);
        kernel_step<<<gridS, block, 0, stream>>>(hin, h_ws, Bt, dst,
            msg_W1, msg_W2, msg_b2, gru_Wih, gru_Whh, gru_bih, gru_bhh);
        hin = h_ws;
    }
    kernel_readout<<<gridB, block, 0, stream>>>(h_ws, ro_W1, ro_b1, ro_W2, ro_b2,
                                                ro_W3, ro_b3, (float*)d_out);
}

// Round 9
// 557.082 us; speedup vs baseline: 1.3059x; 1.1022x over previous
//
#include <hip/hip_runtime.h>
#include <hip/hip_fp16.h>

#define E_EDGES 320000
#define NF 20

typedef float v4 __attribute__((ext_vector_type(4)));
typedef float v2f __attribute__((ext_vector_type(2)));

#if defined(__has_builtin)
# if __has_builtin(__builtin_elementwise_fma)
#  define EWFMA(a,b,c) __builtin_elementwise_fma((a),(b),(c))
# endif
#endif
#ifndef EWFMA
# define EWFMA(a,b,c) ((a)*(b)+(c))
#endif
#if defined(__has_builtin)
# if __has_builtin(__builtin_elementwise_max)
#  define EWMAX(a,b) __builtin_elementwise_max((a),(b))
#  define EWMIN(a,b) __builtin_elementwise_min((a),(b))
# endif
#endif

__device__ __forceinline__ v4 bc4(float s) { return (v4){s, s, s, s}; }
__device__ __forceinline__ v4 v4z() { return (v4){0.f, 0.f, 0.f, 0.f}; }

__device__ __forceinline__ float selu_f(float x) {
    const float scale = 1.0507009873554805f;
    const float alpha = 1.6732632423543772f;
    float p = fmaxf(x, 0.f);
    float m = fminf(x, 0.f);
    float e = __expf(m);
    return fmaf(scale, p, scale * alpha * (e - 1.f));
}
__device__ __forceinline__ float sigmoid_f(float x) {
    return 1.f / (1.f + __expf(-x));
}
// packed selu: pk max/min (or scalarized), scalar exp, pk fma tail
__device__ __forceinline__ v4 selu4(v4 x) {
    const float scale = 1.0507009873554805f;
    const float ka = 1.0507009873554805f * 1.6732632423543772f;
#ifdef EWMAX
    v4 p = EWMAX(x, v4z());
    v4 m = EWMIN(x, v4z());
#else
    v4 p = {fmaxf(x.x,0.f), fmaxf(x.y,0.f), fmaxf(x.z,0.f), fmaxf(x.w,0.f)};
    v4 m = {fminf(x.x,0.f), fminf(x.y,0.f), fminf(x.z,0.f), fminf(x.w,0.f)};
#endif
    v4 e = {__expf(m.x), __expf(m.y), __expf(m.z), __expf(m.w)};
    return EWFMA(bc4(scale), p, EWFMA(bc4(ka), e, bc4(-ka)));
}

__device__ __forceinline__ float hsum4(v4 x) {
    v2f lo = __builtin_shufflevector(x, x, 0, 1);
    v2f hi = __builtin_shufflevector(x, x, 2, 3);
    v2f h = lo + hi;
    return h.x + h.y;
}

__device__ __forceinline__ float dot20v(v4 a0, v4 a1, v4 a2, v4 a3, v4 a4,
                                        const v4* __restrict__ w) {
    v4 w0 = w[0], w1 = w[1], w2 = w[2], w3 = w[3], w4 = w[4];
    v4 x = a0 * w0;
    x = EWFMA(a1, w1, x); x = EWFMA(a2, w2, x);
    x = EWFMA(a3, w3, x); x = EWFMA(a4, w4, x);
    return hsum4(x);
}
// one LDS row read serves BOTH edges, vertical pk-fma then horizontal reduce
__device__ __forceinline__ void dot20_dualv(const v4* __restrict__ w,
    v4 a0, v4 a1, v4 a2, v4 a3, v4 a4,
    v4 b0, v4 b1, v4 b2, v4 b3, v4 b4,
    float& r0, float& r1)
{
    v4 w0 = w[0], w1 = w[1], w2 = w[2], w3 = w[3], w4 = w[4];
    v4 xa = a0 * w0;
    xa = EWFMA(a1, w1, xa); xa = EWFMA(a2, w2, xa);
    xa = EWFMA(a3, w3, xa); xa = EWFMA(a4, w4, xa);
    v4 xb = b0 * w0;
    xb = EWFMA(b1, w1, xb); xb = EWFMA(b2, w2, xb);
    xb = EWFMA(b3, w3, xb); xb = EWFMA(b4, w4, xb);
    r0 = hsum4(xa);
    r1 = hsum4(xb);
}
__device__ __forceinline__ void h8_to_v4x2(uint4 r, v4& lo, v4& hi) {
    float2 fa = __half22float2(__builtin_bit_cast(__half2, r.x));
    float2 fb = __half22float2(__builtin_bit_cast(__half2, r.y));
    float2 fc = __half22float2(__builtin_bit_cast(__half2, r.z));
    float2 fd = __half22float2(__builtin_bit_cast(__half2, r.w));
    lo = (v4){fa.x, fa.y, fb.x, fb.y};
    hi = (v4){fc.x, fc.y, fd.x, fd.y};
}
__device__ __forceinline__ uint4 f8_to_h8(v4 lo, v4 hi) {
    uint4 r;
    r.x = __builtin_bit_cast(unsigned, __floats2half2_rn(lo.x, lo.y));
    r.y = __builtin_bit_cast(unsigned, __floats2half2_rn(lo.z, lo.w));
    r.z = __builtin_bit_cast(unsigned, __floats2half2_rn(hi.x, hi.y));
    r.w = __builtin_bit_cast(unsigned, __floats2half2_rn(hi.z, hi.w));
    return r;
}

#define FOR20(X) \
  X(0, v0.x) X(1, v0.y) X(2, v0.z) X(3, v0.w) \
  X(4, v1.x) X(5, v1.y) X(6, v1.z) X(7, v1.w) \
  X(8, v2.x) X(9, v2.y) X(10, v2.z) X(11, v2.w) \
  X(12, v3.x) X(13, v3.y) X(14, v3.z) X(15, v3.w) \
  X(16, v4v.x) X(17, v4v.y) X(18, v4v.z) X(19, v4v.w)

#define FOR20_2(X) \
  X(0, va0.x, vb0.x) X(1, va0.y, vb0.y) X(2, va0.z, vb0.z) X(3, va0.w, vb0.w) \
  X(4, va1.x, vb1.x) X(5, va1.y, vb1.y) X(6, va1.z, vb1.z) X(7, va1.w, vb1.w) \
  X(8, va2.x, vb2.x) X(9, va2.y, vb2.y) X(10, va2.z, vb2.z) X(11, va2.w, vb2.w) \
  X(12, va3.x, vb3.x) X(13, va3.y, vb3.y) X(14, va3.z, vb3.z) X(15, va3.w, vb3.w) \
  X(16, va4.x, vb4.x) X(17, va4.y, vb4.y) X(18, va4.z, vb4.z) X(19, va4.w, vb4.w)

#define FOR8S2(X) \
  X(0, sa0.x, sb0.x) X(1, sa0.y, sb0.y) X(2, sa0.z, sb0.z) X(3, sa0.w, sb0.w) \
  X(4, sa1.x, sb1.x) X(5, sa1.y, sb1.y) X(6, sa1.z, sb1.z) X(7, sa1.w, sb1.w)

// B[e][o] = sum_f h[e][f] * W1[20+f][o] + b1[o], fp16 output
__global__ void __launch_bounds__(256) kernel_B0(
    const float* __restrict__ h, const float* __restrict__ W1,
    const float* __restrict__ b1, __half* __restrict__ B)
{
    __shared__ __align__(16) float sw[640];
    __shared__ __align__(16) float sbias[32];
    for (int i = threadIdx.x; i < 640; i += 256) sw[i] = W1[640 + i];
    if (threadIdx.x < 32) sbias[threadIdx.x] = b1[threadIdx.x];
    __syncthreads();
    int e = blockIdx.x * 256 + threadIdx.x;
    const v4* hp = reinterpret_cast<const v4*>(h + (size_t)e * NF);
    v4 v0 = hp[0], v1 = hp[1], v2 = hp[2], v3 = hp[3], v4v = hp[4];
    const v4* bi = reinterpret_cast<const v4*>(sbias);
    v4 c0 = bi[0], c1 = bi[1], c2 = bi[2], c3 = bi[3],
       c4 = bi[4], c5 = bi[5], c6 = bi[6], c7 = bi[7];
    #define BSTEP(f, hf) { v4 t_ = bc4(hf); const v4* w_ = (const v4*)&sw[(f)*32]; \
        c0 = EWFMA(t_, w_[0], c0); c1 = EWFMA(t_, w_[1], c1); \
        c2 = EWFMA(t_, w_[2], c2); c3 = EWFMA(t_, w_[3], c3); \
        c4 = EWFMA(t_, w_[4], c4); c5 = EWFMA(t_, w_[5], c5); \
        c6 = EWFMA(t_, w_[6], c6); c7 = EWFMA(t_, w_[7], c7); }
    FOR20(BSTEP)
    #undef BSTEP
    uint4* Bp = reinterpret_cast<uint4*>(B + (size_t)e * 32);
    Bp[0] = f8_to_h8(c0, c1); Bp[1] = f8_to_h8(c2, c3);
    Bp[2] = f8_to_h8(c4, c5); Bp[3] = f8_to_h8(c6, c7);
}

// One step. 4 lanes/quad, 2 edges/thread, fp16 B gather, rolled GRU
// (VGPR=64 shape from R8), all FMA phases on packed fp32 (v_pk_fma_f32).
__global__ void __launch_bounds__(256) kernel_step(
    const float* __restrict__ h_in, float* __restrict__ h_out,
    const __half* __restrict__ Br, const int* __restrict__ dst,
    const float* __restrict__ W1, const float* __restrict__ W2, const float* __restrict__ b2,
    const float* __restrict__ Wih, const float* __restrict__ Whh,
    const float* __restrict__ bih, const float* __restrict__ bhh)
{
    __shared__ __align__(16) float sW1[640];   // rows 0-19 of msg_W1 (20,32)
    __shared__ __align__(16) float sW2[640];   // (32,20)
    __shared__ __align__(16) float sb2v[20];
    __shared__ __align__(16) float sWih[1200]; // (60,20)
    __shared__ __align__(16) float sWhh[1200];
    __shared__ float sbih[60];
    __shared__ float sbhh[60];
    for (int i = threadIdx.x; i < 640; i += 256) { sW1[i] = W1[i]; sW2[i] = W2[i]; }
    for (int i = threadIdx.x; i < 1200; i += 256) { sWih[i] = Wih[i]; sWhh[i] = Whh[i]; }
    if (threadIdx.x < 20) sb2v[threadIdx.x] = b2[threadIdx.x];
    else if (threadIdx.x >= 64 && threadIdx.x < 124) sbih[threadIdx.x - 64] = bih[threadIdx.x - 64];
    else if (threadIdx.x >= 128 && threadIdx.x < 188) sbhh[threadIdx.x - 128] = bhh[threadIdx.x - 128];
    __syncthreads();

    int t = blockIdx.x * 256 + threadIdx.x;
    int p = t >> 2;
    int q = t & 3;
    int ob = q * 8;
    int e0 = p * 2, e1 = p * 2 + 1;

    int2 dd = *reinterpret_cast<const int2*>(dst + e0);
    int d0 = dd.x, d1 = dd.y;

    const v4* hp0 = reinterpret_cast<const v4*>(h_in + (size_t)e0 * NF);
    const v4* hp1 = reinterpret_cast<const v4*>(h_in + (size_t)e1 * NF);
    v4 va0 = hp0[0], va1 = hp0[1], va2 = hp0[2], va3 = hp0[3], va4 = hp0[4];
    v4 vb0 = hp1[0], vb1 = hp1[1], vb2 = hp1[2], vb3 = hp1[3], vb4 = hp1[4];

    // A slices for both edges (shared LDS weight reads, pk-fma)
    v4 aa0 = v4z(), aa1 = v4z(), ab0 = v4z(), ab1 = v4z();
    #define ASTEP2(f, h0, h1) { const v4* w_ = (const v4*)&sW1[(f)*32 + ob]; \
        v4 w0_ = w_[0], w1_ = w_[1]; \
        v4 t0_ = bc4(h0), t1_ = bc4(h1); \
        aa0 = EWFMA(t0_, w0_, aa0); aa1 = EWFMA(t0_, w1_, aa1); \
        ab0 = EWFMA(t1_, w0_, ab0); ab1 = EWFMA(t1_, w1_, ab1); }
    FOR20_2(ASTEP2)
    #undef ASTEP2

    // gather 16 fp16 rows per edge; 1 dwordx4 per row per edge = lane's 8 chans
    const uint4* Bp0 = reinterpret_cast<const uint4*>(Br) + (size_t)d0 * 64 + q;
    const uint4* Bp1 = reinterpret_cast<const uint4*>(Br) + (size_t)d1 * 64 + q;
    v4 sa0 = v4z(), sa1 = v4z(), sb0 = v4z(), sb1 = v4z();
    #pragma unroll 4
    for (int k = 0; k < 16; k++) {
        uint4 rA = Bp0[k * 4];
        uint4 rB = Bp1[k * 4];
        v4 loA, hiA, loB, hiB;
        h8_to_v4x2(rA, loA, hiA);
        h8_to_v4x2(rB, loB, hiB);
        sa0 = sa0 + selu4(aa0 + loA);
        sa1 = sa1 + selu4(aa1 + hiA);
        sb0 = sb0 + selu4(ab0 + loB);
        sb1 = sb1 + selu4(ab1 + hiB);
    }

    // partial agg (shared W2 rows, pk-fma)
    v4 ga0 = v4z(), ga1 = v4z(), ga2 = v4z(), ga3 = v4z(), ga4 = v4z();
    v4 gb0 = v4z(), gb1 = v4z(), gb2 = v4z(), gb3 = v4z(), gb4 = v4z();
    #define AGGS2(j, c0_, c1_) { const v4* w_ = (const v4*)&sW2[(ob + (j)) * 20]; \
        v4 w0_ = w_[0], w1_ = w_[1], w2_ = w_[2], w3_ = w_[3], w4_ = w_[4]; \
        v4 u_ = bc4(c0_), vv_ = bc4(c1_); \
        ga0 = EWFMA(u_, w0_, ga0); ga1 = EWFMA(u_, w1_, ga1); ga2 = EWFMA(u_, w2_, ga2); \
        ga3 = EWFMA(u_, w3_, ga3); ga4 = EWFMA(u_, w4_, ga4); \
        gb0 = EWFMA(vv_, w0_, gb0); gb1 = EWFMA(vv_, w1_, gb1); gb2 = EWFMA(vv_, w2_, gb2); \
        gb3 = EWFMA(vv_, w3_, gb3); gb4 = EWFMA(vv_, w4_, gb4); }
    FOR8S2(AGGS2)
    #undef AGGS2

    // quad butterfly (component shfl, packed adds)
    #define BF1(r_, m_) { v4 t_ = { __shfl_xor(r_.x, m_), __shfl_xor(r_.y, m_), \
                                    __shfl_xor(r_.z, m_), __shfl_xor(r_.w, m_) }; \
                          r_ = r_ + t_; }
    #define BFLY(m_) BF1(ga0, m_) BF1(ga1, m_) BF1(ga2, m_) BF1(ga3, m_) BF1(ga4, m_) \
                     BF1(gb0, m_) BF1(gb1, m_) BF1(gb2, m_) BF1(gb3, m_) BF1(gb4, m_)
    BFLY(1)
    BFLY(2)
    #undef BFLY
    #undef BF1

    {
        const v4* b2p = reinterpret_cast<const v4*>(sb2v);
        v4 sixteen = bc4(16.f);
        v4 c0 = b2p[0], c1 = b2p[1], c2 = b2p[2], c3 = b2p[3], c4 = b2p[4];
        ga0 = EWFMA(sixteen, c0, ga0); ga1 = EWFMA(sixteen, c1, ga1); ga2 = EWFMA(sixteen, c2, ga2);
        ga3 = EWFMA(sixteen, c3, ga3); ga4 = EWFMA(sixteen, c4, ga4);
        gb0 = EWFMA(sixteen, c0, gb0); gb1 = EWFMA(sixteen, c1, gb1); gb2 = EWFMA(sixteen, c2, gb2);
        gb3 = EWFMA(sixteen, c3, gb3); gb4 = EWFMA(sixteen, c4, gb4);
    }

    // GRU: 5 channels per lane, ROLLED (dynamic index -> LDS only; VGPR=64)
    for (int i = 0; i < 5; i++) {
        int c = q * 5 + i;
        float ir0, ir1, iz0, iz1, in0, in1, hr0, hr1, hz0, hz1, hn0, hn1;
        dot20_dualv((const v4*)&sWih[c * 20],        ga0, ga1, ga2, ga3, ga4,
                    gb0, gb1, gb2, gb3, gb4, ir0, ir1);
        dot20_dualv((const v4*)&sWih[(20 + c) * 20], ga0, ga1, ga2, ga3, ga4,
                    gb0, gb1, gb2, gb3, gb4, iz0, iz1);
        dot20_dualv((const v4*)&sWih[(40 + c) * 20], ga0, ga1, ga2, ga3, ga4,
                    gb0, gb1, gb2, gb3, gb4, in0, in1);
        dot20_dualv((const v4*)&sWhh[c * 20],        va0, va1, va2, va3, va4,
                    vb0, vb1, vb2, vb3, vb4, hr0, hr1);
        dot20_dualv((const v4*)&sWhh[(20 + c) * 20], va0, va1, va2, va3, va4,
                    vb0, vb1, vb2, vb3, vb4, hz0, hz1);
        dot20_dualv((const v4*)&sWhh[(40 + c) * 20], va0, va1, va2, va3, va4,
                    vb0, vb1, vb2, vb3, vb4, hn0, hn1);
        float bi_r = sbih[c], bi_z = sbih[20 + c], bi_n = sbih[40 + c];
        float bh_r = sbhh[c], bh_z = sbhh[20 + c], bh_n = sbhh[40 + c];
        {
            float r = sigmoid_f(bi_r + ir0 + bh_r + hr0);
            float z = sigmoid_f(bi_z + iz0 + bh_z + hz0);
            float xn = bi_n + in0 + r * (bh_n + hn0);
            xn = fminf(fmaxf(xn, -20.f), 20.f);
            float tt = __expf(2.f * xn);
            float n = (tt - 1.f) / (tt + 1.f);
            float hc = h_in[(size_t)e0 * NF + c];
            h_out[(size_t)e0 * NF + c] = (1.f - z) * n + z * hc;
        }
        {
            float r = sigmoid_f(bi_r + ir1 + bh_r + hr1);
            float z = sigmoid_f(bi_z + iz1 + bh_z + hz1);
            float xn = bi_n + in1 + r * (bh_n + hn1);
            xn = fminf(fmaxf(xn, -20.f), 20.f);
            float tt = __expf(2.f * xn);
            float n = (tt - 1.f) / (tt + 1.f);
            float hc = h_in[(size_t)e1 * NF + c];
            h_out[(size_t)e1 * NF + c] = (1.f - z) * n + z * hc;
        }
    }
}

__global__ void __launch_bounds__(256) kernel_readout(
    const float* __restrict__ h,
    const float* __restrict__ W1, const float* __restrict__ b1,
    const float* __restrict__ W2, const float* __restrict__ b2,
    const float* __restrict__ W3, const float* __restrict__ b3,
    float* __restrict__ out)
{
    __shared__ __align__(16) float sW1t[1280]; // transposed: (64,20)
    __shared__ float sb1[64];
    __shared__ __align__(16) float sW2[2048];  // (64,32)
    __shared__ __align__(16) float sb2v[32];
    __shared__ __align__(16) float sW3[32];
    __shared__ float sb3;
    for (int i = threadIdx.x; i < 1280; i += 256) {
        int f = i >> 6, o = i & 63;
        sW1t[o * 20 + f] = W1[i];
    }
    for (int i = threadIdx.x; i < 2048; i += 256) sW2[i] = W2[i];
    if (threadIdx.x < 64) sb1[threadIdx.x] = b1[threadIdx.x];
    else if (threadIdx.x >= 64 && threadIdx.x < 96) sb2v[threadIdx.x - 64] = b2[threadIdx.x - 64];
    else if (threadIdx.x >= 96 && threadIdx.x < 128) sW3[threadIdx.x - 96] = W3[threadIdx.x - 96];
    if (threadIdx.x == 128) sb3 = b3[0];
    __syncthreads();

    int e = blockIdx.x * 256 + threadIdx.x;
    const v4* hp = reinterpret_cast<const v4*>(h + (size_t)e * NF);
    v4 v0 = hp[0], v1 = hp[1], v2 = hp[2], v3 = hp[3], v4v = hp[4];

    const v4* b2p = reinterpret_cast<const v4*>(sb2v);
    v4 x20 = b2p[0], x21 = b2p[1], x22 = b2p[2], x23 = b2p[3],
       x24 = b2p[4], x25 = b2p[5], x26 = b2p[6], x27 = b2p[7];
    for (int o = 0; o < 64; o++) {
        float x1 = sb1[o] + dot20v(v0, v1, v2, v3, v4v, (const v4*)&sW1t[o * 20]);
        x1 = selu_f(x1);
        v4 xb = bc4(x1);
        const v4* w = (const v4*)&sW2[o * 32];
        x20 = EWFMA(xb, w[0], x20); x21 = EWFMA(xb, w[1], x21);
        x22 = EWFMA(xb, w[2], x22); x23 = EWFMA(xb, w[3], x23);
        x24 = EWFMA(xb, w[4], x24); x25 = EWFMA(xb, w[5], x25);
        x26 = EWFMA(xb, w[6], x26); x27 = EWFMA(xb, w[7], x27);
    }
    const v4* w3p = reinterpret_cast<const v4*>(sW3);
    v4 accv = selu4(x20) * w3p[0];
    accv = EWFMA(selu4(x21), w3p[1], accv);
    accv = EWFMA(selu4(x22), w3p[2], accv);
    accv = EWFMA(selu4(x23), w3p[3], accv);
    accv = EWFMA(selu4(x24), w3p[4], accv);
    accv = EWFMA(selu4(x25), w3p[5], accv);
    accv = EWFMA(selu4(x26), w3p[6], accv);
    accv = EWFMA(selu4(x27), w3p[7], accv);
    float acc = sb3 + hsum4(accv);
    float sp = fmaxf(acc, 0.f) + log1pf(__expf(-fabsf(acc)));
    float w = sp + 0.1f;
    w = fminf(fmaxf(w, 0.1f), 10.f);
    out[e] = w;
}

extern "C" void kernel_launch(void* const* d_in, const int* in_sizes, int n_in,
                              void* d_out, int out_size, void* d_ws, size_t ws_size,
                              hipStream_t stream) {
    const float* edge_attr = (const float*)d_in[0];
    const float* msg_W1   = (const float*)d_in[1];
    const float* msg_b1   = (const float*)d_in[2];
    const float* msg_W2   = (const float*)d_in[3];
    const float* msg_b2   = (const float*)d_in[4];
    const float* gru_Wih  = (const float*)d_in[5];
    const float* gru_Whh  = (const float*)d_in[6];
    const float* gru_bih  = (const float*)d_in[7];
    const float* gru_bhh  = (const float*)d_in[8];
    const float* ro_W1    = (const float*)d_in[9];
    const float* ro_b1    = (const float*)d_in[10];
    const float* ro_W2    = (const float*)d_in[11];
    const float* ro_b2    = (const float*)d_in[12];
    const float* ro_W3    = (const float*)d_in[13];
    const float* ro_b3    = (const float*)d_in[14];
    const int* edge_index = (const int*)d_in[15];
    const int* dst = edge_index + E_EDGES;   // row 1 of (2,E)

    float*  h_ws = (float*)d_ws;                                  // E*20 f32
    __half* Bt   = (__half*)(h_ws + (size_t)E_EDGES * NF);        // E*32 f16

    dim3 block(256);
    dim3 gridB(E_EDGES / 256);
    dim3 gridS(E_EDGES * 2 / 256);     // 4 lanes per 2-edge pair

    const float* hin = edge_attr;
    for (int s = 0; s < 4; s++) {
        kernel_B0<<<gridB, block, 0, stream>>>(hin, msg_W1, msg_b1, Bt);
        kernel_step<<<gridS, block, 0, stream>>>(hin, h_ws, Bt, dst,
            msg_W1, msg_W2, msg_b2, gru_Wih, gru_Whh, gru_bih, gru_bhh);
        hin = h_ws;
    }
    kernel_readout<<<gridB, block, 0, stream>>>(h_ws, ro_W1, ro_b1, ro_W2, ro_b2,
                                                ro_W3, ro_b3, (float*)d_out);
}